// Round 16
// baseline (465.647 us; speedup 1.0000x reference)
//
#include <hip/hip_runtime.h>

#define N_SERVICES 50000
#define N_PAD      50048   // 782*64
#define N_EDGES    1600000
#define N_CTX      6144    // BATCH*CONTEXT
#define EMB        32
#define BATCH      2048
#define FIN        128     // (CONTEXT+1)*EMB
#define N_TILES    782
#define BM         128
#define M_CHUNKS   16      // 2048 / BM
#define N_CHAINS   64
#define GEMM_BLKS  (M_CHUNKS * N_CHAINS)   // 1024
#define RUN_BASE   12      // 782 = 64*12 + 14
#define RUN_EXTRA  14

// --- CSR build geometry ---
#define CC         64                  // count chunks (single-pass full-node hist)
#define ECC        (N_EDGES / CC)      // 25000 edges per count chunk
#define I4CC       (ECC / 4)           // 6250
#define PSTR       50000               // partial stride (nodes, ushort)
#define HWORDS     25000               // packed hist words (2 nodes/word)
#define FC         16                  // fill chunks per range (= 4 count chunks)
#define EFC        (N_EDGES / FC)      // 100000
#define I4FC       (EFC / 4)           // 25000
#define RANGE      8192                // fill node range (2^13)
#define R_RANGES   7

typedef __attribute__((ext_vector_type(4))) float f32x4;
typedef __attribute__((ext_vector_type(2))) float f32x2;
typedef __attribute__((ext_vector_type(8))) short short8;

__device__ inline unsigned short f2bf(float f) {
    unsigned u = __float_as_uint(f);
    unsigned r = (u + 0x7FFFu + ((u >> 16) & 1u)) >> 16;
    return (unsigned short)r;
}
__device__ inline float bf2f(unsigned short b) {
    return __uint_as_float(((unsigned)b) << 16);
}

// ---------------- count: ONE pass over dst, packed full-node LDS hist ----------
// 64 blocks; block c histograms its 25K edges over all 50000 nodes (100KB LDS,
// 2 nodes packed per uint; per-chunk per-node counts ~<=8, no carry risk).

__global__ __launch_bounds__(256) void k_count(const int* __restrict__ dst,
                                               unsigned short* __restrict__ partial) {
    __shared__ unsigned int hist[HWORDS];
    int t = threadIdx.x, c = blockIdx.x;
    for (int i = t; i < HWORDS; i += 256) hist[i] = 0;
    __syncthreads();
    const int4* d4 = (const int4*)(dst + c * ECC);
    for (int i = t; i < I4CC; i += 256) {
        int4 d = d4[i];
        atomicAdd(&hist[d.x >> 1], 1u << ((d.x & 1) * 16));
        atomicAdd(&hist[d.y >> 1], 1u << ((d.y & 1) * 16));
        atomicAdd(&hist[d.z >> 1], 1u << ((d.z & 1) * 16));
        atomicAdd(&hist[d.w >> 1], 1u << ((d.w & 1) * 16));
    }
    __syncthreads();
    ushort2* p = (ushort2*)(partial + (size_t)c * PSTR);
    for (int i = t; i < HWORDS; i += 256) {
        unsigned v = hist[i];
        ushort2 u;
        u.x = (unsigned short)(v & 0xffff);
        u.y = (unsigned short)(v >> 16);
        p[i] = u;
    }
}

// ---------------- scan pass 1; chunk-reduce + dis folded in ----------------

__global__ void k_scan_block(const unsigned short* __restrict__ partial,
                             float* __restrict__ dis,
                             int* __restrict__ tmp, int* __restrict__ blocksum) {
    __shared__ int s[256];
    int t = threadIdx.x, i = blockIdx.x * 256 + t;
    int v = 0;
    if (i < N_SERVICES) {
#pragma unroll 8
        for (int c = 0; c < CC; ++c) v += partial[(size_t)c * PSTR + i];
        dis[i] = rsqrtf((float)(v + 1));  // +1 self-loop
    }
    s[t] = v;
    __syncthreads();
#pragma unroll
    for (int o = 1; o < 256; o <<= 1) {
        int x = 0;
        if (t >= o) x = s[t - o];
        __syncthreads();
        if (t >= o) s[t] += x;
        __syncthreads();
    }
    if (i < N_SERVICES) tmp[i] = s[t] - v;       // exclusive within block
    if (t == 255) blocksum[blockIdx.x] = s[255];
}

// ---------------- fused: scan finish (+ctx list build)  ∥  layer-1 transform ----

__global__ __launch_bounds__(256) void k_scanfin_tf(
    const int* __restrict__ tmp, const int* __restrict__ blocksum,
    int* __restrict__ row_start,
    const int* __restrict__ ctx_idx, int* __restrict__ mask,
    int* __restrict__ ctx_list, int* __restrict__ ctx_count,
    const float* __restrict__ in, const float* __restrict__ W1,
    const float* __restrict__ dis, unsigned short* __restrict__ h) {
    __shared__ int s[256];
    __shared__ float Ws[EMB][EMB + 1];
    __shared__ float rows[8][EMB];
    int t = threadIdx.x;

    if (blockIdx.x < 196) {
        int v = (t < 196) ? blocksum[t] : 0;
        s[t] = v;
        __syncthreads();
#pragma unroll
        for (int o = 1; o < 256; o <<= 1) {
            int x = 0;
            if (t >= o) x = s[t - o];
            __syncthreads();
            if (t >= o) s[t] += x;
            __syncthreads();
        }
        int prefix = (blockIdx.x == 0) ? 0 : s[blockIdx.x - 1];
        int i = blockIdx.x * 256 + t;
        if (i < N_SERVICES) row_start[i] = tmp[i] + prefix;
        if (i < N_CTX) {
            int n = ctx_idx[i];
            if (atomicExch(&mask[n], 1) == 0)
                ctx_list[atomicAdd(ctx_count, 1)] = n;
        }
        if (i == 0) row_start[N_SERVICES] = N_EDGES;
    } else {
        int j = t & 31, li = t >> 5;
        for (int i = t; i < EMB * EMB; i += 256) Ws[i >> 5][i & 31] = W1[i];
        int node = (blockIdx.x - 196) * 8 + li;
        if (node < N_SERVICES) rows[li][j] = in[node * EMB + j];
        __syncthreads();
        if (node < N_SERVICES) {
            float acc = 0.f;
#pragma unroll
            for (int k = 0; k < EMB; ++k) acc = fmaf(rows[li][k], Ws[k][j], acc);
            h[node * EMB + j] = f2bf(acc * dis[node]);
        }
    }
}

// ---------------- fill: in-LDS cursors (row_start + partial prefix), no k_cursor ----
// grid 7 ranges x 16 fill-chunks. Fill chunk fc covers count chunks 4fc..4fc+3.

__global__ __launch_bounds__(256) void k_fill(const int* __restrict__ src,
                                              const int* __restrict__ dst,
                                              const int* __restrict__ row_start,
                                              const unsigned short* __restrict__ partial,
                                              int* __restrict__ csr_src) {
    __shared__ int cur[RANGE];
    int t = threadIdx.x;
    int r  = blockIdx.x / FC;
    int fc = blockIdx.x % FC;
    int base = r * RANGE;
    int cend = fc * 4;                 // count chunks before this fill chunk
    for (int i = t; i < RANGE; i += 256) {
        int n = base + i;
        int v = 0;
        if (n < N_SERVICES) {
            v = row_start[n];
            for (int cc = 0; cc < cend; ++cc)
                v += partial[(size_t)cc * PSTR + n];
        }
        cur[i] = v;
    }
    __syncthreads();
    const int4* d4 = (const int4*)(dst + fc * EFC);
    const int4* s4 = (const int4*)(src + fc * EFC);
    for (int i = t; i < I4FC; i += 256) {
        int4 d = d4[i];
        int4 s = s4[i];
        if ((d.x >> 13) == r) csr_src[atomicAdd(&cur[d.x & (RANGE - 1)], 1)] = s.x;
        if ((d.y >> 13) == r) csr_src[atomicAdd(&cur[d.y & (RANGE - 1)], 1)] = s.y;
        if ((d.z >> 13) == r) csr_src[atomicAdd(&cur[d.z & (RANGE - 1)], 1)] = s.z;
        if ((d.w >> 13) == r) csr_src[atomicAdd(&cur[d.w & (RANGE - 1)], 1)] = s.w;
    }
}

// ---------------- fused layer-1 agg + ReLU + layer-2 transform ----------------

__global__ __launch_bounds__(256) void k_agg_tf(
    const int* __restrict__ row_start, const int* __restrict__ csr_src,
    const float* __restrict__ dis, const unsigned int* __restrict__ h2,
    const float* __restrict__ b, const float* __restrict__ W2,
    unsigned short* __restrict__ hout) {
    __shared__ float gr[16][33];
    __shared__ float Ws[32][33];
    int t = threadIdx.x;
    for (int i = t; i < EMB * EMB; i += 256) Ws[i >> 5][i & 31] = W2[i];

    int j2 = t & 15;                       // dim pair
    int local = t >> 4;
    int node = blockIdx.x * 16 + local;
    int e = row_start[node], e1 = row_start[node + 1];
    float al0 = 0.f, ah0 = 0.f, al1 = 0.f, ah1 = 0.f;
    float al2 = 0.f, ah2 = 0.f, al3 = 0.f, ah3 = 0.f;
    for (; e + 4 <= e1; e += 4) {
        int s0 = csr_src[e], s1 = csr_src[e + 1], s2 = csr_src[e + 2], s3 = csr_src[e + 3];
        unsigned v0 = h2[s0 * 16 + j2], v1 = h2[s1 * 16 + j2];
        unsigned v2 = h2[s2 * 16 + j2], v3 = h2[s3 * 16 + j2];
        al0 += bf2f((unsigned short)(v0 & 0xffff)); ah0 += bf2f((unsigned short)(v0 >> 16));
        al1 += bf2f((unsigned short)(v1 & 0xffff)); ah1 += bf2f((unsigned short)(v1 >> 16));
        al2 += bf2f((unsigned short)(v2 & 0xffff)); ah2 += bf2f((unsigned short)(v2 >> 16));
        al3 += bf2f((unsigned short)(v3 & 0xffff)); ah3 += bf2f((unsigned short)(v3 >> 16));
    }
    for (; e < e1; ++e) {
        unsigned v0 = h2[csr_src[e] * 16 + j2];
        al0 += bf2f((unsigned short)(v0 & 0xffff)); ah0 += bf2f((unsigned short)(v0 >> 16));
    }
    float dn = dis[node];
    unsigned vn = h2[node * 16 + j2];
    float lo = dn * ((al0 + al1) + (al2 + al3) + bf2f((unsigned short)(vn & 0xffff))) + b[j2 * 2];
    float hi = dn * ((ah0 + ah1) + (ah2 + ah3) + bf2f((unsigned short)(vn >> 16))) + b[j2 * 2 + 1];
    gr[local][j2 * 2]     = fmaxf(lo, 0.f);
    gr[local][j2 * 2 + 1] = fmaxf(hi, 0.f);
    __syncthreads();

    int d = t & 31;
    int l0 = t >> 5;                       // 0..7
    float s0 = 0.f, s1 = 0.f;
#pragma unroll
    for (int k = 0; k < EMB; ++k) {
        float w = Ws[k][d];
        s0 = fmaf(gr[l0][k], w, s0);
        s1 = fmaf(gr[l0 + 8][k], w, s1);
    }
    int n0 = blockIdx.x * 16 + l0;
    hout[(size_t)n0 * EMB + d]       = f2bf(s0 * dis[n0]);
    hout[(size_t)(n0 + 8) * EMB + d] = f2bf(s1 * dis[n0 + 8]);
}

// ---------------- layer-2 agg over the compact ctx list ----------------

__global__ void k_agg_ctx(const int* __restrict__ row_start, const int* __restrict__ csr_src,
                          const float* __restrict__ dis, const unsigned int* __restrict__ h2,
                          const float* __restrict__ b, const int* __restrict__ ctx_list,
                          const int* __restrict__ ctx_count, float* __restrict__ out) {
    int t = threadIdx.x;
    int j2 = t & 15;
    int slot = blockIdx.x * 16 + (t >> 4);
    if (slot >= *ctx_count) return;
    int node = ctx_list[slot];
    int e = row_start[node], e1 = row_start[node + 1];
    float al0 = 0.f, ah0 = 0.f, al1 = 0.f, ah1 = 0.f;
    float al2 = 0.f, ah2 = 0.f, al3 = 0.f, ah3 = 0.f;
    for (; e + 4 <= e1; e += 4) {
        int s0 = csr_src[e], s1 = csr_src[e + 1], s2 = csr_src[e + 2], s3 = csr_src[e + 3];
        unsigned v0 = h2[s0 * 16 + j2], v1 = h2[s1 * 16 + j2];
        unsigned v2 = h2[s2 * 16 + j2], v3 = h2[s3 * 16 + j2];
        al0 += bf2f((unsigned short)(v0 & 0xffff)); ah0 += bf2f((unsigned short)(v0 >> 16));
        al1 += bf2f((unsigned short)(v1 & 0xffff)); ah1 += bf2f((unsigned short)(v1 >> 16));
        al2 += bf2f((unsigned short)(v2 & 0xffff)); ah2 += bf2f((unsigned short)(v2 >> 16));
        al3 += bf2f((unsigned short)(v3 & 0xffff)); ah3 += bf2f((unsigned short)(v3 >> 16));
    }
    for (; e < e1; ++e) {
        unsigned v0 = h2[csr_src[e] * 16 + j2];
        al0 += bf2f((unsigned short)(v0 & 0xffff)); ah0 += bf2f((unsigned short)(v0 >> 16));
    }
    float dn = dis[node];
    unsigned vn = h2[node * 16 + j2];
    float lo = dn * ((al0 + al1) + (al2 + al3) + bf2f((unsigned short)(vn & 0xffff))) + b[j2 * 2];
    float hi = dn * ((ah0 + ah1) + (ah2 + ah3) + bf2f((unsigned short)(vn >> 16))) + b[j2 * 2 + 1];
    f32x2 o; o.x = lo; o.y = hi;
    *(f32x2*)&out[node * EMB + j2 * 2] = o;
}

// ---------------- feature gather (emit bf16) ----------------

__global__ void k_gather(const int* __restrict__ user_idx, const int* __restrict__ ctx_idx,
                         const float* __restrict__ user_emb, const float* __restrict__ g2,
                         unsigned short* __restrict__ x) {
    int t = blockIdx.x * 256 + threadIdx.x;  // grid exact: BATCH*FIN
    int b = t >> 7, p = t & 127;
    float v;
    if (p < EMB) {
        v = user_emb[user_idx[b] * EMB + p];
    } else {
        int c = (p - EMB) >> 5, j = p & 31;
        v = g2[ctx_idx[b * 3 + c] * EMB + j];
    }
    x[t] = f2bf(v);
}

// ---------------- fc_W transpose+convert + zero mask/ctx_count ----------------

__global__ __launch_bounds__(256) void k_cvtW(const float* __restrict__ W,
                                              short* __restrict__ Wt,
                                              int* __restrict__ mask,
                                              int* __restrict__ ctx_count) {
    int gid = blockIdx.x * 256 + threadIdx.x;
    if (gid < N_SERVICES) mask[gid] = 0;
    if (gid == 0) *ctx_count = 0;

    __shared__ short lds[128][33];
    int t = threadIdx.x;
    int n0 = blockIdx.x * 32;
    int nx = t & 31;
    int n  = n0 + nx;
    int kg = t >> 5;                 // 0..7
#pragma unroll
    for (int r = 0; r < 16; ++r) {
        int k = r * 8 + kg;
        float v = (n < N_SERVICES) ? W[k * N_SERVICES + n] : 0.f;
        lds[k][nx] = (short)f2bf(v);
    }
    __syncthreads();
    int nr = t >> 3;                 // 0..31
    int kc = (t & 7) * 16;
    short tmp[16];
#pragma unroll
    for (int i = 0; i < 16; ++i) tmp[i] = lds[kc + i][nr];
    short8* dstp = (short8*)(Wt + (size_t)(n0 + nr) * FIN + kc);
    dstp[0] = *(short8*)&tmp[0];
    dstp[1] = *(short8*)&tmp[8];
}

// ---------------- final GEMM: r12-exact (dbuf LDS, NT stores) ----------------

__global__ __launch_bounds__(256, 2) void k_gemm3(
    const short* __restrict__ A, const short* __restrict__ Bt,
    const float* __restrict__ bias, float* __restrict__ out) {
    __shared__ float tile[2][BM][68];      // 2 x 34,816 B
    int t = threadIdx.x;
    int w = t >> 6;
    int l = t & 63;
    int lr = l & 15;
    int lg = l >> 4;
    int mc = blockIdx.x >> 6;
    int c  = blockIdx.x & (N_CHAINS - 1);
    int nt0 = c * RUN_BASE + (c < RUN_EXTRA ? c : RUN_EXTRA);
    int cnt = RUN_BASE + (c < RUN_EXTRA ? 1 : 0);
    int m_base = mc * BM;

    short8 a[8][4];
#pragma unroll
    for (int mi = 0; mi < 8; ++mi) {
        const short* arow = A + (size_t)(m_base + mi * 16 + lr) * FIN + lg * 8;
#pragma unroll
        for (int ks = 0; ks < 4; ++ks) a[mi][ks] = *(const short8*)(arow + ks * 32);
    }

    const short* bbase = Bt + (size_t)(w * 16 + lr) * FIN + lg * 8;
    short8 b0[4], b1[4];
    {
        const short* p = bbase + (size_t)nt0 * 64 * FIN;
#pragma unroll
        for (int ks = 0; ks < 4; ++ks) b0[ks] = *(const short8*)(p + ks * 32);
    }

    int scol = lr * 4;
    int p = 0;

    for (int i = 0; i < cnt; ++i) {
        int nt = nt0 + i;
        if (i + 1 < cnt) {
            const short* pp = bbase + (size_t)(nt + 1) * 64 * FIN;
#pragma unroll
            for (int ks = 0; ks < 4; ++ks) b1[ks] = *(const short8*)(pp + ks * 32);
        }
#pragma unroll
        for (int mi = 0; mi < 8; ++mi) {
            f32x4 acc = {};
#pragma unroll
            for (int ks = 0; ks < 4; ++ks)
                acc = __builtin_amdgcn_mfma_f32_16x16x32_bf16(b0[ks], a[mi][ks], acc, 0, 0, 0);
            *(f32x4*)&tile[p][mi * 16 + lr][w * 16 + lg * 4] = acc;
        }
        __syncthreads();                   // single barrier per iteration
        {
            int gcol = nt * 64 + scol;
            bool ok = gcol < N_SERVICES;
            f32x4 bv = {};
            if (ok) bv = *(const f32x4*)&bias[gcol];
            float* ob = out + (size_t)m_base * N_SERVICES + gcol;
#pragma unroll
            for (int si = 0; si < 8; ++si) {
                int row = w * 32 + si * 4 + lg;
                f32x4 v = *(const f32x4*)&tile[p][row][scol] + bv;
                if (ok)
                    __builtin_nontemporal_store(
                        v, (f32x4*)(ob + (size_t)row * N_SERVICES));
            }
        }
        p ^= 1;
#pragma unroll
        for (int ks = 0; ks < 4; ++ks) b0[ks] = b1[ks];
    }
}

// ---------------- launch ----------------

extern "C" void kernel_launch(void* const* d_in, const int* in_sizes, int n_in,
                              void* d_out, int out_size, void* d_ws, size_t ws_size,
                              hipStream_t stream) {
    const int*   user_idx    = (const int*)d_in[0];
    const int*   ctx_idx     = (const int*)d_in[1];
    const int*   ei          = (const int*)d_in[2];
    const float* user_emb    = (const float*)d_in[3];
    const float* service_emb = (const float*)d_in[4];
    const float* W1          = (const float*)d_in[5];
    const float* b1          = (const float*)d_in[6];
    const float* W2          = (const float*)d_in[7];
    const float* b2          = (const float*)d_in[8];
    const float* fcW         = (const float*)d_in[9];
    const float* fcb         = (const float*)d_in[10];
    float* out = (float*)d_out;

    const int* src = ei;
    const int* dst = ei + N_EDGES;

    char* ws = (char*)d_ws;
    float*          dis       = (float*)(ws);                    // 200,000
    unsigned short* h1        = (unsigned short*)(ws + 200000);  // 3,200,000 (bf16 h1')
    unsigned short* h2b       = (unsigned short*)(ws + 3400000); // 3,200,000 (bf16 h2')
    float*          g         = (float*)(ws + 6600000);          // 6,400,000 (g2, ctx rows)
    unsigned short* partial   = (unsigned short*)(ws + 6600000); // 6,400,000 overlay (dead before k_agg_ctx writes g)
    unsigned short* xb        = (unsigned short*)(ws + 13000000);//   524,288
    short*          Wt        = (short*)(ws + 13524288);         // 12,812,288
    int*            row_start = (int*)(ws + 26336576);           // 200,004
    int*            csr_src   = (int*)(ws + 26736580);           // 6,400,000
    int*            tmp       = (int*)(ws + 26736580);           // 200,000 overlay (dead before k_fill)
    int*            blocksum  = (int*)(ws + 33136580);           // 1,024
    int*            mask      = (int*)(ws + 33137604);           // 200,000
    int*            ctx_list  = (int*)(ws + 33337604);           // 24,576
    int*            ctx_count = (int*)(ws + 33362180);           // 4     (total ~33.4 MB)

    // cvtW also zeroes mask + ctx_count (runs first)
    k_cvtW<<<N_PAD / 32, 256, 0, stream>>>(fcW, Wt, mask, ctx_count);

    // CSR build — no global atomics, dst read once
    k_count<<<CC, 256, 0, stream>>>(dst, partial);
    k_scan_block<<<196, 256, 0, stream>>>(partial, dis, tmp, blocksum);
    k_scanfin_tf<<<196 + 6250, 256, 0, stream>>>(tmp, blocksum, row_start,
                                                 ctx_idx, mask, ctx_list, ctx_count,
                                                 service_emb, W1, dis, h1);
    k_fill<<<R_RANGES * FC, 256, 0, stream>>>(src, dst, row_start, partial, csr_src);

    // fused layer-1 agg + ReLU + layer-2 transform (g1 never leaves LDS)
    k_agg_tf<<<3125, 256, 0, stream>>>(row_start, csr_src, dis,
                                       (const unsigned int*)h1, b1, W2, h2b);
    // layer-2 agg over compact ctx list (g overlays partial — partial dead now)
    k_agg_ctx<<<N_CTX / 16, 256, 0, stream>>>(row_start, csr_src, dis,
                                              (const unsigned int*)h2b, b2,
                                              ctx_list, ctx_count, g);

    k_gather<<<BATCH * FIN / 256, 256, 0, stream>>>(user_idx, ctx_idx, user_emb, g, xb);

    k_gemm3<<<GEMM_BLKS, 256, 0, stream>>>((const short*)xb, Wt, fcb, out);
}

// Round 17
// 285.997 us; speedup vs baseline: 1.6282x; 1.6282x over previous
//
#include <hip/hip_runtime.h>

#define N_SERVICES 50000
#define N_PAD      50048   // 782*64
#define N_EDGES    1600000
#define N_CTX      6144    // BATCH*CONTEXT
#define EMB        32
#define BATCH      2048
#define FIN        128     // (CONTEXT+1)*EMB
#define N_TILES    782
#define BM         128
#define M_CHUNKS   16      // 2048 / BM
#define N_CHAINS   64
#define GEMM_BLKS  (M_CHUNKS * N_CHAINS)   // 1024
#define RUN_BASE   12      // 782 = 64*12 + 14
#define RUN_EXTRA  14

// --- tiled CSR build geometry ---
#define RANGE      8192            // nodes per range (2^13)
#define R_RANGES   7               // ceil(50000/8192)
#define PSTRIDE    (R_RANGES * RANGE)  // 57344 (padded node stride)
#define C_CHUNKS   16
#define EPC        (N_EDGES / C_CHUNKS)   // 100000 edges/chunk
#define I4PC       (EPC / 4)              // 25000 int4/chunk

typedef __attribute__((ext_vector_type(4))) float f32x4;
typedef __attribute__((ext_vector_type(2))) float f32x2;
typedef __attribute__((ext_vector_type(8))) short short8;

__device__ inline unsigned short f2bf(float f) {
    unsigned u = __float_as_uint(f);
    unsigned r = (u + 0x7FFFu + ((u >> 16) & 1u)) >> 16;
    return (unsigned short)r;
}
__device__ inline float bf2f(unsigned short b) {
    return __uint_as_float(((unsigned)b) << 16);
}

// ---------------- tiled count: LDS histogram, NO global atomics ----------------
// grid R_RANGES*C_CHUNKS = 112. block (r,c): histogram chunk c over node range r.

__global__ __launch_bounds__(256) void k_tiled_count(const int* __restrict__ dst,
                                                     unsigned short* __restrict__ partial) {
    __shared__ int hist[RANGE];
    int t = threadIdx.x;
    int r = blockIdx.x / C_CHUNKS;
    int c = blockIdx.x % C_CHUNKS;
    for (int i = t; i < RANGE; i += 256) hist[i] = 0;
    __syncthreads();
    const int4* d4 = (const int4*)(dst + c * EPC);
    for (int i = t; i < I4PC; i += 256) {
        int4 d = d4[i];
        if ((d.x >> 13) == r) atomicAdd(&hist[d.x & (RANGE - 1)], 1);
        if ((d.y >> 13) == r) atomicAdd(&hist[d.y & (RANGE - 1)], 1);
        if ((d.z >> 13) == r) atomicAdd(&hist[d.z & (RANGE - 1)], 1);
        if ((d.w >> 13) == r) atomicAdd(&hist[d.w & (RANGE - 1)], 1);
    }
    __syncthreads();
    unsigned short* p = partial + (size_t)c * PSTRIDE + r * RANGE;
    for (int i = t; i < RANGE; i += 256) p[i] = (unsigned short)hist[i];
}

// ---------------- scan pass 1; chunk-reduce + dis folded in ----------------

__global__ void k_scan_block(const unsigned short* __restrict__ partial,
                             float* __restrict__ dis,
                             int* __restrict__ tmp, int* __restrict__ blocksum) {
    __shared__ int s[256];
    int t = threadIdx.x, i = blockIdx.x * 256 + t;
    int v = 0;
    if (i < N_SERVICES) {
#pragma unroll
        for (int c = 0; c < C_CHUNKS; ++c) v += partial[(size_t)c * PSTRIDE + i];
        dis[i] = rsqrtf((float)(v + 1));  // +1 self-loop
    }
    s[t] = v;
    __syncthreads();
#pragma unroll
    for (int o = 1; o < 256; o <<= 1) {
        int x = 0;
        if (t >= o) x = s[t - o];
        __syncthreads();
        if (t >= o) s[t] += x;
        __syncthreads();
    }
    if (i < N_SERVICES) tmp[i] = s[t] - v;       // exclusive within block
    if (t == 255) blocksum[blockIdx.x] = s[255];
}

// ---------------- fused: scan finish (+ctx list build)  ∥  layer-1 transform ----

__global__ __launch_bounds__(256) void k_scanfin_tf(
    const int* __restrict__ tmp, const int* __restrict__ blocksum,
    int* __restrict__ row_start,
    const int* __restrict__ ctx_idx, int* __restrict__ mask,
    int* __restrict__ ctx_list, int* __restrict__ ctx_count,
    const float* __restrict__ in, const float* __restrict__ W1,
    const float* __restrict__ dis, unsigned short* __restrict__ h) {
    __shared__ int s[256];
    __shared__ float Ws[EMB][EMB + 1];
    __shared__ float rows[8][EMB];
    int t = threadIdx.x;

    if (blockIdx.x < 196) {
        int v = (t < 196) ? blocksum[t] : 0;
        s[t] = v;
        __syncthreads();
#pragma unroll
        for (int o = 1; o < 256; o <<= 1) {
            int x = 0;
            if (t >= o) x = s[t - o];
            __syncthreads();
            if (t >= o) s[t] += x;
            __syncthreads();
        }
        int prefix = (blockIdx.x == 0) ? 0 : s[blockIdx.x - 1];
        int i = blockIdx.x * 256 + t;
        if (i < N_SERVICES) row_start[i] = tmp[i] + prefix;
        if (i < N_CTX) {
            int n = ctx_idx[i];
            if (atomicExch(&mask[n], 1) == 0)
                ctx_list[atomicAdd(ctx_count, 1)] = n;
        }
        if (i == 0) row_start[N_SERVICES] = N_EDGES;
    } else {
        int j = t & 31, li = t >> 5;
        for (int i = t; i < EMB * EMB; i += 256) Ws[i >> 5][i & 31] = W1[i];
        int node = (blockIdx.x - 196) * 8 + li;
        if (node < N_SERVICES) rows[li][j] = in[node * EMB + j];
        __syncthreads();
        if (node < N_SERVICES) {
            float acc = 0.f;
#pragma unroll
            for (int k = 0; k < EMB; ++k) acc = fmaf(rows[li][k], Ws[k][j], acc);
            h[node * EMB + j] = f2bf(acc * dis[node]);
        }
    }
}

// ---------------- per-chunk absolute cursors (prefix over chunks) ----------------

__global__ void k_cursor(const int* __restrict__ row_start,
                         const unsigned short* __restrict__ partial,
                         int* __restrict__ cursor_int) {
    int i = blockIdx.x * 256 + threadIdx.x;
    if (i >= N_SERVICES) return;
    int s = row_start[i];
#pragma unroll
    for (int c = 0; c < C_CHUNKS; ++c) {
        int cnt = partial[(size_t)c * PSTRIDE + i];
        cursor_int[(size_t)c * PSTRIDE + i] = s;
        s += cnt;
    }
}

// ---------------- fill: LDS cursors, XCD-co-scheduled by range ----------------
// grid 8*C_CHUNKS = 128; r = bid&7 (r=7 exits), c = bid>>3. All 16 blocks of a
// range share bid%8 -> same XCD -> the range's ~900KB scattered-write window
// stays in ONE XCD's 4MB L2 (RMW absorbed), instead of thrashing all 8.

__global__ __launch_bounds__(256) void k_fill(const int* __restrict__ src,
                                              const int* __restrict__ dst,
                                              const int* __restrict__ cursor_int,
                                              int* __restrict__ csr_src) {
    int r = blockIdx.x & 7;
    if (r >= R_RANGES) return;
    int c = blockIdx.x >> 3;
    __shared__ int cur[RANGE];
    int t = threadIdx.x;
    const int* cbase = cursor_int + (size_t)c * PSTRIDE + r * RANGE;
    for (int i = t; i < RANGE; i += 256) cur[i] = cbase[i];
    __syncthreads();
    const int4* d4 = (const int4*)(dst + c * EPC);
    const int4* s4 = (const int4*)(src + c * EPC);
    for (int i = t; i < I4PC; i += 256) {
        int4 d = d4[i];
        int4 s = s4[i];
        if ((d.x >> 13) == r) csr_src[atomicAdd(&cur[d.x & (RANGE - 1)], 1)] = s.x;
        if ((d.y >> 13) == r) csr_src[atomicAdd(&cur[d.y & (RANGE - 1)], 1)] = s.y;
        if ((d.z >> 13) == r) csr_src[atomicAdd(&cur[d.z & (RANGE - 1)], 1)] = s.z;
        if ((d.w >> 13) == r) csr_src[atomicAdd(&cur[d.w & (RANGE - 1)], 1)] = s.w;
    }
}

// ---------------- fused layer-1 agg + ReLU + layer-2 transform ----------------

__global__ __launch_bounds__(256) void k_agg_tf(
    const int* __restrict__ row_start, const int* __restrict__ csr_src,
    const float* __restrict__ dis, const unsigned int* __restrict__ h2,
    const float* __restrict__ b, const float* __restrict__ W2,
    unsigned short* __restrict__ hout) {
    __shared__ float gr[16][33];
    __shared__ float Ws[32][33];
    int t = threadIdx.x;
    for (int i = t; i < EMB * EMB; i += 256) Ws[i >> 5][i & 31] = W2[i];

    int j2 = t & 15;                       // dim pair
    int local = t >> 4;
    int node = blockIdx.x * 16 + local;
    int e = row_start[node], e1 = row_start[node + 1];
    float al0 = 0.f, ah0 = 0.f, al1 = 0.f, ah1 = 0.f;
    float al2 = 0.f, ah2 = 0.f, al3 = 0.f, ah3 = 0.f;
    for (; e + 4 <= e1; e += 4) {
        int s0 = csr_src[e], s1 = csr_src[e + 1], s2 = csr_src[e + 2], s3 = csr_src[e + 3];
        unsigned v0 = h2[s0 * 16 + j2], v1 = h2[s1 * 16 + j2];
        unsigned v2 = h2[s2 * 16 + j2], v3 = h2[s3 * 16 + j2];
        al0 += bf2f((unsigned short)(v0 & 0xffff)); ah0 += bf2f((unsigned short)(v0 >> 16));
        al1 += bf2f((unsigned short)(v1 & 0xffff)); ah1 += bf2f((unsigned short)(v1 >> 16));
        al2 += bf2f((unsigned short)(v2 & 0xffff)); ah2 += bf2f((unsigned short)(v2 >> 16));
        al3 += bf2f((unsigned short)(v3 & 0xffff)); ah3 += bf2f((unsigned short)(v3 >> 16));
    }
    for (; e < e1; ++e) {
        unsigned v0 = h2[csr_src[e] * 16 + j2];
        al0 += bf2f((unsigned short)(v0 & 0xffff)); ah0 += bf2f((unsigned short)(v0 >> 16));
    }
    float dn = dis[node];
    unsigned vn = h2[node * 16 + j2];
    float lo = dn * ((al0 + al1) + (al2 + al3) + bf2f((unsigned short)(vn & 0xffff))) + b[j2 * 2];
    float hi = dn * ((ah0 + ah1) + (ah2 + ah3) + bf2f((unsigned short)(vn >> 16))) + b[j2 * 2 + 1];
    gr[local][j2 * 2]     = fmaxf(lo, 0.f);
    gr[local][j2 * 2 + 1] = fmaxf(hi, 0.f);
    __syncthreads();

    int d = t & 31;
    int l0 = t >> 5;                       // 0..7
    float s0 = 0.f, s1 = 0.f;
#pragma unroll
    for (int k = 0; k < EMB; ++k) {
        float w = Ws[k][d];
        s0 = fmaf(gr[l0][k], w, s0);
        s1 = fmaf(gr[l0 + 8][k], w, s1);
    }
    int n0 = blockIdx.x * 16 + l0;
    hout[(size_t)n0 * EMB + d]       = f2bf(s0 * dis[n0]);
    hout[(size_t)(n0 + 8) * EMB + d] = f2bf(s1 * dis[n0 + 8]);
}

// ---------------- layer-2 agg over the compact ctx list ----------------

__global__ void k_agg_ctx(const int* __restrict__ row_start, const int* __restrict__ csr_src,
                          const float* __restrict__ dis, const unsigned int* __restrict__ h2,
                          const float* __restrict__ b, const int* __restrict__ ctx_list,
                          const int* __restrict__ ctx_count, float* __restrict__ out) {
    int t = threadIdx.x;
    int j2 = t & 15;
    int slot = blockIdx.x * 16 + (t >> 4);
    if (slot >= *ctx_count) return;
    int node = ctx_list[slot];
    int e = row_start[node], e1 = row_start[node + 1];
    float al0 = 0.f, ah0 = 0.f, al1 = 0.f, ah1 = 0.f;
    float al2 = 0.f, ah2 = 0.f, al3 = 0.f, ah3 = 0.f;
    for (; e + 4 <= e1; e += 4) {
        int s0 = csr_src[e], s1 = csr_src[e + 1], s2 = csr_src[e + 2], s3 = csr_src[e + 3];
        unsigned v0 = h2[s0 * 16 + j2], v1 = h2[s1 * 16 + j2];
        unsigned v2 = h2[s2 * 16 + j2], v3 = h2[s3 * 16 + j2];
        al0 += bf2f((unsigned short)(v0 & 0xffff)); ah0 += bf2f((unsigned short)(v0 >> 16));
        al1 += bf2f((unsigned short)(v1 & 0xffff)); ah1 += bf2f((unsigned short)(v1 >> 16));
        al2 += bf2f((unsigned short)(v2 & 0xffff)); ah2 += bf2f((unsigned short)(v2 >> 16));
        al3 += bf2f((unsigned short)(v3 & 0xffff)); ah3 += bf2f((unsigned short)(v3 >> 16));
    }
    for (; e < e1; ++e) {
        unsigned v0 = h2[csr_src[e] * 16 + j2];
        al0 += bf2f((unsigned short)(v0 & 0xffff)); ah0 += bf2f((unsigned short)(v0 >> 16));
    }
    float dn = dis[node];
    unsigned vn = h2[node * 16 + j2];
    float lo = dn * ((al0 + al1) + (al2 + al3) + bf2f((unsigned short)(vn & 0xffff))) + b[j2 * 2];
    float hi = dn * ((ah0 + ah1) + (ah2 + ah3) + bf2f((unsigned short)(vn >> 16))) + b[j2 * 2 + 1];
    f32x2 o; o.x = lo; o.y = hi;
    *(f32x2*)&out[node * EMB + j2 * 2] = o;
}

// ---------------- feature gather (emit bf16) ----------------

__global__ void k_gather(const int* __restrict__ user_idx, const int* __restrict__ ctx_idx,
                         const float* __restrict__ user_emb, const float* __restrict__ g2,
                         unsigned short* __restrict__ x) {
    int t = blockIdx.x * 256 + threadIdx.x;  // grid exact: BATCH*FIN
    int b = t >> 7, p = t & 127;
    float v;
    if (p < EMB) {
        v = user_emb[user_idx[b] * EMB + p];
    } else {
        int c = (p - EMB) >> 5, j = p & 31;
        v = g2[ctx_idx[b * 3 + c] * EMB + j];
    }
    x[t] = f2bf(v);
}

// ---------------- fc_W transpose+convert + zero mask/ctx_count ----------------

__global__ __launch_bounds__(256) void k_cvtW(const float* __restrict__ W,
                                              short* __restrict__ Wt,
                                              int* __restrict__ mask,
                                              int* __restrict__ ctx_count) {
    int gid = blockIdx.x * 256 + threadIdx.x;
    if (gid < N_SERVICES) mask[gid] = 0;
    if (gid == 0) *ctx_count = 0;

    __shared__ short lds[128][33];
    int t = threadIdx.x;
    int n0 = blockIdx.x * 32;
    int nx = t & 31;
    int n  = n0 + nx;
    int kg = t >> 5;                 // 0..7
#pragma unroll
    for (int r = 0; r < 16; ++r) {
        int k = r * 8 + kg;
        float v = (n < N_SERVICES) ? W[k * N_SERVICES + n] : 0.f;
        lds[k][nx] = (short)f2bf(v);
    }
    __syncthreads();
    int nr = t >> 3;                 // 0..31
    int kc = (t & 7) * 16;
    short tmp[16];
#pragma unroll
    for (int i = 0; i < 16; ++i) tmp[i] = lds[kc + i][nr];
    short8* dstp = (short8*)(Wt + (size_t)(n0 + nr) * FIN + kc);
    dstp[0] = *(short8*)&tmp[0];
    dstp[1] = *(short8*)&tmp[8];
}

// ---------------- final GEMM: r12-exact (dbuf LDS, NT stores) ----------------

__global__ __launch_bounds__(256, 2) void k_gemm3(
    const short* __restrict__ A, const short* __restrict__ Bt,
    const float* __restrict__ bias, float* __restrict__ out) {
    __shared__ float tile[2][BM][68];      // 2 x 34,816 B
    int t = threadIdx.x;
    int w = t >> 6;
    int l = t & 63;
    int lr = l & 15;
    int lg = l >> 4;
    int mc = blockIdx.x >> 6;
    int c  = blockIdx.x & (N_CHAINS - 1);
    int nt0 = c * RUN_BASE + (c < RUN_EXTRA ? c : RUN_EXTRA);
    int cnt = RUN_BASE + (c < RUN_EXTRA ? 1 : 0);
    int m_base = mc * BM;

    short8 a[8][4];
#pragma unroll
    for (int mi = 0; mi < 8; ++mi) {
        const short* arow = A + (size_t)(m_base + mi * 16 + lr) * FIN + lg * 8;
#pragma unroll
        for (int ks = 0; ks < 4; ++ks) a[mi][ks] = *(const short8*)(arow + ks * 32);
    }

    const short* bbase = Bt + (size_t)(w * 16 + lr) * FIN + lg * 8;
    short8 b0[4], b1[4];
    {
        const short* p = bbase + (size_t)nt0 * 64 * FIN;
#pragma unroll
        for (int ks = 0; ks < 4; ++ks) b0[ks] = *(const short8*)(p + ks * 32);
    }

    int scol = lr * 4;
    int p = 0;

    for (int i = 0; i < cnt; ++i) {
        int nt = nt0 + i;
        if (i + 1 < cnt) {
            const short* pp = bbase + (size_t)(nt + 1) * 64 * FIN;
#pragma unroll
            for (int ks = 0; ks < 4; ++ks) b1[ks] = *(const short8*)(pp + ks * 32);
        }
#pragma unroll
        for (int mi = 0; mi < 8; ++mi) {
            f32x4 acc = {};
#pragma unroll
            for (int ks = 0; ks < 4; ++ks)
                acc = __builtin_amdgcn_mfma_f32_16x16x32_bf16(b0[ks], a[mi][ks], acc, 0, 0, 0);
            *(f32x4*)&tile[p][mi * 16 + lr][w * 16 + lg * 4] = acc;
        }
        __syncthreads();                   // single barrier per iteration
        {
            int gcol = nt * 64 + scol;
            bool ok = gcol < N_SERVICES;
            f32x4 bv = {};
            if (ok) bv = *(const f32x4*)&bias[gcol];
            float* ob = out + (size_t)m_base * N_SERVICES + gcol;
#pragma unroll
            for (int si = 0; si < 8; ++si) {
                int row = w * 32 + si * 4 + lg;
                f32x4 v = *(const f32x4*)&tile[p][row][scol] + bv;
                if (ok)
                    __builtin_nontemporal_store(
                        v, (f32x4*)(ob + (size_t)row * N_SERVICES));
            }
        }
        p ^= 1;
#pragma unroll
        for (int ks = 0; ks < 4; ++ks) b0[ks] = b1[ks];
    }
}

// ---------------- launch ----------------

extern "C" void kernel_launch(void* const* d_in, const int* in_sizes, int n_in,
                              void* d_out, int out_size, void* d_ws, size_t ws_size,
                              hipStream_t stream) {
    const int*   user_idx    = (const int*)d_in[0];
    const int*   ctx_idx     = (const int*)d_in[1];
    const int*   ei          = (const int*)d_in[2];
    const float* user_emb    = (const float*)d_in[3];
    const float* service_emb = (const float*)d_in[4];
    const float* W1          = (const float*)d_in[5];
    const float* b1          = (const float*)d_in[6];
    const float* W2          = (const float*)d_in[7];
    const float* b2          = (const float*)d_in[8];
    const float* fcW         = (const float*)d_in[9];
    const float* fcb         = (const float*)d_in[10];
    float* out = (float*)d_out;

    const int* src = ei;
    const int* dst = ei + N_EDGES;

    char* ws = (char*)d_ws;
    float*          dis        = (float*)(ws);                    // 200,000
    unsigned short* h1         = (unsigned short*)(ws + 200000);  // 3,200,000 (bf16 h1')
    unsigned short* h2b        = (unsigned short*)(ws + 3400000); // 3,200,000 (bf16 h2')
    float*          g          = (float*)(ws + 6600000);          // 6,400,000 (g2, ctx rows)
    int*            cursor_int = (int*)(ws + 6600000);            // 3,670,016 overlay (dead before k_agg_ctx)
    unsigned short* xb         = (unsigned short*)(ws + 13000000);//   524,288
    short*          Wt         = (short*)(ws + 13524288);         // 12,812,288
    int*            row_start  = (int*)(ws + 26336576);           // 200,004
    int*            csr_src    = (int*)(ws + 26736580);           // 6,400,000
    int*            tmp        = (int*)(ws + 26736580);           // 200,000 overlay (dead before k_fill)
    int*            blocksum   = (int*)(ws + 33136580);           // 1,024
    int*            mask       = (int*)(ws + 33137604);           // 200,000
    int*            ctx_list   = (int*)(ws + 33337604);           // 24,576
    int*            ctx_count  = (int*)(ws + 33362180);           // 4
    unsigned short* partial    = (unsigned short*)(ws + 33362192);// 1,835,008 (total ~35.2 MB)

    // cvtW also zeroes mask + ctx_count (runs first)
    k_cvtW<<<N_PAD / 32, 256, 0, stream>>>(fcW, Wt, mask, ctx_count);

    // CSR build — no global atomics
    k_tiled_count<<<R_RANGES * C_CHUNKS, 256, 0, stream>>>(dst, partial);
    k_scan_block<<<196, 256, 0, stream>>>(partial, dis, tmp, blocksum);
    k_scanfin_tf<<<196 + 6250, 256, 0, stream>>>(tmp, blocksum, row_start,
                                                 ctx_idx, mask, ctx_list, ctx_count,
                                                 service_emb, W1, dis, h1);
    k_cursor<<<196, 256, 0, stream>>>(row_start, partial, cursor_int);
    // fill: 128 blocks, range = bid&7 -> all blocks of a range on ONE XCD
    k_fill<<<8 * C_CHUNKS, 256, 0, stream>>>(src, dst, cursor_int, csr_src);

    // fused layer-1 agg + ReLU + layer-2 transform (g1 never leaves LDS)
    k_agg_tf<<<3125, 256, 0, stream>>>(row_start, csr_src, dis,
                                       (const unsigned int*)h1, b1, W2, h2b);
    // layer-2 agg over compact ctx list (overwrites cursor_int region — dead)
    k_agg_ctx<<<N_CTX / 16, 256, 0, stream>>>(row_start, csr_src, dis,
                                              (const unsigned int*)h2b, b2,
                                              ctx_list, ctx_count, g);

    k_gather<<<BATCH * FIN / 256, 256, 0, stream>>>(user_idx, ctx_idx, user_emb, g, xb);

    k_gemm3<<<GEMM_BLKS, 256, 0, stream>>>((const short*)xb, Wt, fcb, out);
}

// Round 18
// 219.805 us; speedup vs baseline: 2.1185x; 1.3011x over previous
//
#include <hip/hip_runtime.h>

#define N_SERVICES 50000
#define N_PAD      50048   // 782*64
#define N_EDGES    1600000
#define N_CTX      6144    // BATCH*CONTEXT
#define EMB        32
#define BATCH      2048
#define FIN        128     // (CONTEXT+1)*EMB
#define N_TILES    782
#define BM         128
#define M_CHUNKS   16      // 2048 / BM
#define N_CHAINS   64
#define GEMM_BLKS  (M_CHUNKS * N_CHAINS)   // 1024
#define RUN_BASE   12      // 782 = 64*12 + 14
#define RUN_EXTRA  14

// --- tiled CSR build geometry ---
#define RANGE      8192                   // nodes per range (2^13)
#define R_RANGES   7                      // ceil(50000/8192)
#define C_CHUNKS   64
#define PSTR       50000                  // partial stride (nodes, ushort)
#define EPC        (N_EDGES / C_CHUNKS)   // 25000 edges/chunk
#define I4PC       (EPC / 4)              // 6250 int4/chunk

typedef __attribute__((ext_vector_type(4))) float f32x4;
typedef __attribute__((ext_vector_type(2))) float f32x2;
typedef __attribute__((ext_vector_type(8))) short short8;

__device__ inline unsigned short f2bf(float f) {
    unsigned u = __float_as_uint(f);
    unsigned r = (u + 0x7FFFu + ((u >> 16) & 1u)) >> 16;
    return (unsigned short)r;
}
__device__ inline float bf2f(unsigned short b) {
    return __uint_as_float(((unsigned)b) << 16);
}

// ---------------- tiled count: LDS histogram, NO global atomics ----------------
// grid R_RANGES*C_CHUNKS = 448. block (r,c): histogram chunk c over node range r.

__global__ __launch_bounds__(256) void k_tiled_count(const int* __restrict__ dst,
                                                     unsigned short* __restrict__ partial) {
    __shared__ int hist[RANGE];
    int t = threadIdx.x;
    int r = blockIdx.x / C_CHUNKS;
    int c = blockIdx.x % C_CHUNKS;
    for (int i = t; i < RANGE; i += 256) hist[i] = 0;
    __syncthreads();
    const int4* d4 = (const int4*)(dst + c * EPC);
    for (int i = t; i < I4PC; i += 256) {
        int4 d = d4[i];
        if ((d.x >> 13) == r) atomicAdd(&hist[d.x & (RANGE - 1)], 1);
        if ((d.y >> 13) == r) atomicAdd(&hist[d.y & (RANGE - 1)], 1);
        if ((d.z >> 13) == r) atomicAdd(&hist[d.z & (RANGE - 1)], 1);
        if ((d.w >> 13) == r) atomicAdd(&hist[d.w & (RANGE - 1)], 1);
    }
    __syncthreads();
    int base = r * RANGE;
    unsigned short* p = partial + (size_t)c * PSTR;
    for (int i = t; i < RANGE; i += 256) {
        int n = base + i;
        if (n < N_SERVICES) p[n] = (unsigned short)hist[i];
    }
}

// ---------------- scan pass 1; chunk-reduce + dis folded in ----------------

__global__ void k_scan_block(const unsigned short* __restrict__ partial,
                             float* __restrict__ dis,
                             int* __restrict__ tmp, int* __restrict__ blocksum) {
    __shared__ int s[256];
    int t = threadIdx.x, i = blockIdx.x * 256 + t;
    int v = 0;
    if (i < N_SERVICES) {
#pragma unroll 8
        for (int c = 0; c < C_CHUNKS; ++c) v += partial[(size_t)c * PSTR + i];
        dis[i] = rsqrtf((float)(v + 1));  // +1 self-loop
    }
    s[t] = v;
    __syncthreads();
#pragma unroll
    for (int o = 1; o < 256; o <<= 1) {
        int x = 0;
        if (t >= o) x = s[t - o];
        __syncthreads();
        if (t >= o) s[t] += x;
        __syncthreads();
    }
    if (i < N_SERVICES) tmp[i] = s[t] - v;       // exclusive within block
    if (t == 255) blocksum[blockIdx.x] = s[255];
}

// ---------------- fused: scan finish + ctx list + IN-PLACE offsets ∥ transform ----
// blocks 0..195: finish row_start, build ctx_list, and convert partial counts ->
// exclusive per-node chunk offsets (in place, ushort: offsets <= degree).
// blocks 196..6445: h1' = (service_emb @ W1)*dis  (bf16).

__global__ __launch_bounds__(256) void k_scanfin_tf(
    const int* __restrict__ tmp, const int* __restrict__ blocksum,
    int* __restrict__ row_start,
    const int* __restrict__ ctx_idx, int* __restrict__ mask,
    int* __restrict__ ctx_list, int* __restrict__ ctx_count,
    unsigned short* __restrict__ partial,
    const float* __restrict__ in, const float* __restrict__ W1,
    const float* __restrict__ dis, unsigned short* __restrict__ h) {
    __shared__ int s[256];
    __shared__ float Ws[EMB][EMB + 1];
    __shared__ float rows[8][EMB];
    int t = threadIdx.x;

    if (blockIdx.x < 196) {
        int v = (t < 196) ? blocksum[t] : 0;
        s[t] = v;
        __syncthreads();
#pragma unroll
        for (int o = 1; o < 256; o <<= 1) {
            int x = 0;
            if (t >= o) x = s[t - o];
            __syncthreads();
            if (t >= o) s[t] += x;
            __syncthreads();
        }
        int prefix = (blockIdx.x == 0) ? 0 : s[blockIdx.x - 1];
        int i = blockIdx.x * 256 + t;
        if (i < N_SERVICES) {
            row_start[i] = tmp[i] + prefix;
            // in-place: counts -> exclusive chunk offsets for node i
            int acc = 0;
#pragma unroll 8
            for (int c = 0; c < C_CHUNKS; ++c) {
                size_t idx = (size_t)c * PSTR + i;
                int cnt = partial[idx];
                partial[idx] = (unsigned short)acc;
                acc += cnt;
            }
        }
        if (i < N_CTX) {
            int n = ctx_idx[i];
            if (atomicExch(&mask[n], 1) == 0)
                ctx_list[atomicAdd(ctx_count, 1)] = n;
        }
        if (i == 0) row_start[N_SERVICES] = N_EDGES;
    } else {
        int j = t & 31, li = t >> 5;
        for (int i = t; i < EMB * EMB; i += 256) Ws[i >> 5][i & 31] = W1[i];
        int node = (blockIdx.x - 196) * 8 + li;
        if (node < N_SERVICES) rows[li][j] = in[node * EMB + j];
        __syncthreads();
        if (node < N_SERVICES) {
            float acc = 0.f;
#pragma unroll
            for (int k = 0; k < EMB; ++k) acc = fmaf(rows[li][k], Ws[k][j], acc);
            h[node * EMB + j] = f2bf(acc * dis[node]);
        }
    }
}

// ---------------- fill: LDS cursors from row_start + in-place offsets ----------
// grid R_RANGES*C_CHUNKS = 448. cur[i] = row_start[n] + offsets[c][n].

__global__ __launch_bounds__(256) void k_fill(const int* __restrict__ src,
                                              const int* __restrict__ dst,
                                              const int* __restrict__ row_start,
                                              const unsigned short* __restrict__ partial,
                                              int* __restrict__ csr_src) {
    __shared__ int cur[RANGE];
    int t = threadIdx.x;
    int r = blockIdx.x / C_CHUNKS;
    int c = blockIdx.x % C_CHUNKS;
    int base = r * RANGE;
    const unsigned short* off = partial + (size_t)c * PSTR;
    for (int i = t; i < RANGE; i += 256) {
        int n = base + i;
        cur[i] = (n < N_SERVICES) ? (row_start[n] + off[n]) : 0;
    }
    __syncthreads();
    const int4* d4 = (const int4*)(dst + c * EPC);
    const int4* s4 = (const int4*)(src + c * EPC);
    for (int i = t; i < I4PC; i += 256) {
        int4 d = d4[i];
        int4 s = s4[i];
        if ((d.x >> 13) == r) csr_src[atomicAdd(&cur[d.x & (RANGE - 1)], 1)] = s.x;
        if ((d.y >> 13) == r) csr_src[atomicAdd(&cur[d.y & (RANGE - 1)], 1)] = s.y;
        if ((d.z >> 13) == r) csr_src[atomicAdd(&cur[d.z & (RANGE - 1)], 1)] = s.z;
        if ((d.w >> 13) == r) csr_src[atomicAdd(&cur[d.w & (RANGE - 1)], 1)] = s.w;
    }
}

// ---------------- fused layer-1 agg + ReLU + layer-2 transform ----------------

__global__ __launch_bounds__(256) void k_agg_tf(
    const int* __restrict__ row_start, const int* __restrict__ csr_src,
    const float* __restrict__ dis, const unsigned int* __restrict__ h2,
    const float* __restrict__ b, const float* __restrict__ W2,
    unsigned short* __restrict__ hout) {
    __shared__ float gr[16][33];
    __shared__ float Ws[32][33];
    int t = threadIdx.x;
    for (int i = t; i < EMB * EMB; i += 256) Ws[i >> 5][i & 31] = W2[i];

    int j2 = t & 15;                       // dim pair
    int local = t >> 4;
    int node = blockIdx.x * 16 + local;
    int e = row_start[node], e1 = row_start[node + 1];
    float al0 = 0.f, ah0 = 0.f, al1 = 0.f, ah1 = 0.f;
    float al2 = 0.f, ah2 = 0.f, al3 = 0.f, ah3 = 0.f;
    for (; e + 4 <= e1; e += 4) {
        int s0 = csr_src[e], s1 = csr_src[e + 1], s2 = csr_src[e + 2], s3 = csr_src[e + 3];
        unsigned v0 = h2[s0 * 16 + j2], v1 = h2[s1 * 16 + j2];
        unsigned v2 = h2[s2 * 16 + j2], v3 = h2[s3 * 16 + j2];
        al0 += bf2f((unsigned short)(v0 & 0xffff)); ah0 += bf2f((unsigned short)(v0 >> 16));
        al1 += bf2f((unsigned short)(v1 & 0xffff)); ah1 += bf2f((unsigned short)(v1 >> 16));
        al2 += bf2f((unsigned short)(v2 & 0xffff)); ah2 += bf2f((unsigned short)(v2 >> 16));
        al3 += bf2f((unsigned short)(v3 & 0xffff)); ah3 += bf2f((unsigned short)(v3 >> 16));
    }
    for (; e < e1; ++e) {
        unsigned v0 = h2[csr_src[e] * 16 + j2];
        al0 += bf2f((unsigned short)(v0 & 0xffff)); ah0 += bf2f((unsigned short)(v0 >> 16));
    }
    float dn = dis[node];
    unsigned vn = h2[node * 16 + j2];
    float lo = dn * ((al0 + al1) + (al2 + al3) + bf2f((unsigned short)(vn & 0xffff))) + b[j2 * 2];
    float hi = dn * ((ah0 + ah1) + (ah2 + ah3) + bf2f((unsigned short)(vn >> 16))) + b[j2 * 2 + 1];
    gr[local][j2 * 2]     = fmaxf(lo, 0.f);
    gr[local][j2 * 2 + 1] = fmaxf(hi, 0.f);
    __syncthreads();

    int d = t & 31;
    int l0 = t >> 5;                       // 0..7
    float s0 = 0.f, s1 = 0.f;
#pragma unroll
    for (int k = 0; k < EMB; ++k) {
        float w = Ws[k][d];
        s0 = fmaf(gr[l0][k], w, s0);
        s1 = fmaf(gr[l0 + 8][k], w, s1);
    }
    int n0 = blockIdx.x * 16 + l0;
    hout[(size_t)n0 * EMB + d]       = f2bf(s0 * dis[n0]);
    hout[(size_t)(n0 + 8) * EMB + d] = f2bf(s1 * dis[n0 + 8]);
}

// ---------------- layer-2 agg over the compact ctx list ----------------

__global__ void k_agg_ctx(const int* __restrict__ row_start, const int* __restrict__ csr_src,
                          const float* __restrict__ dis, const unsigned int* __restrict__ h2,
                          const float* __restrict__ b, const int* __restrict__ ctx_list,
                          const int* __restrict__ ctx_count, float* __restrict__ out) {
    int t = threadIdx.x;
    int j2 = t & 15;
    int slot = blockIdx.x * 16 + (t >> 4);
    if (slot >= *ctx_count) return;
    int node = ctx_list[slot];
    int e = row_start[node], e1 = row_start[node + 1];
    float al0 = 0.f, ah0 = 0.f, al1 = 0.f, ah1 = 0.f;
    float al2 = 0.f, ah2 = 0.f, al3 = 0.f, ah3 = 0.f;
    for (; e + 4 <= e1; e += 4) {
        int s0 = csr_src[e], s1 = csr_src[e + 1], s2 = csr_src[e + 2], s3 = csr_src[e + 3];
        unsigned v0 = h2[s0 * 16 + j2], v1 = h2[s1 * 16 + j2];
        unsigned v2 = h2[s2 * 16 + j2], v3 = h2[s3 * 16 + j2];
        al0 += bf2f((unsigned short)(v0 & 0xffff)); ah0 += bf2f((unsigned short)(v0 >> 16));
        al1 += bf2f((unsigned short)(v1 & 0xffff)); ah1 += bf2f((unsigned short)(v1 >> 16));
        al2 += bf2f((unsigned short)(v2 & 0xffff)); ah2 += bf2f((unsigned short)(v2 >> 16));
        al3 += bf2f((unsigned short)(v3 & 0xffff)); ah3 += bf2f((unsigned short)(v3 >> 16));
    }
    for (; e < e1; ++e) {
        unsigned v0 = h2[csr_src[e] * 16 + j2];
        al0 += bf2f((unsigned short)(v0 & 0xffff)); ah0 += bf2f((unsigned short)(v0 >> 16));
    }
    float dn = dis[node];
    unsigned vn = h2[node * 16 + j2];
    float lo = dn * ((al0 + al1) + (al2 + al3) + bf2f((unsigned short)(vn & 0xffff))) + b[j2 * 2];
    float hi = dn * ((ah0 + ah1) + (ah2 + ah3) + bf2f((unsigned short)(vn >> 16))) + b[j2 * 2 + 1];
    f32x2 o; o.x = lo; o.y = hi;
    *(f32x2*)&out[node * EMB + j2 * 2] = o;
}

// ---------------- feature gather (emit bf16) ----------------

__global__ void k_gather(const int* __restrict__ user_idx, const int* __restrict__ ctx_idx,
                         const float* __restrict__ user_emb, const float* __restrict__ g2,
                         unsigned short* __restrict__ x) {
    int t = blockIdx.x * 256 + threadIdx.x;  // grid exact: BATCH*FIN
    int b = t >> 7, p = t & 127;
    float v;
    if (p < EMB) {
        v = user_emb[user_idx[b] * EMB + p];
    } else {
        int c = (p - EMB) >> 5, j = p & 31;
        v = g2[ctx_idx[b * 3 + c] * EMB + j];
    }
    x[t] = f2bf(v);
}

// ---------------- fc_W transpose+convert + zero mask/ctx_count ----------------

__global__ __launch_bounds__(256) void k_cvtW(const float* __restrict__ W,
                                              short* __restrict__ Wt,
                                              int* __restrict__ mask,
                                              int* __restrict__ ctx_count) {
    int gid = blockIdx.x * 256 + threadIdx.x;
    if (gid < N_SERVICES) mask[gid] = 0;
    if (gid == 0) *ctx_count = 0;

    __shared__ short lds[128][33];
    int t = threadIdx.x;
    int n0 = blockIdx.x * 32;
    int nx = t & 31;
    int n  = n0 + nx;
    int kg = t >> 5;                 // 0..7
#pragma unroll
    for (int r = 0; r < 16; ++r) {
        int k = r * 8 + kg;
        float v = (n < N_SERVICES) ? W[k * N_SERVICES + n] : 0.f;
        lds[k][nx] = (short)f2bf(v);
    }
    __syncthreads();
    int nr = t >> 3;                 // 0..31
    int kc = (t & 7) * 16;
    short tmp[16];
#pragma unroll
    for (int i = 0; i < 16; ++i) tmp[i] = lds[kc + i][nr];
    short8* dstp = (short8*)(Wt + (size_t)(n0 + nr) * FIN + kc);
    dstp[0] = *(short8*)&tmp[0];
    dstp[1] = *(short8*)&tmp[8];
}

// ---------------- final GEMM: r12-exact (dbuf LDS, NT stores) ----------------

__global__ __launch_bounds__(256, 2) void k_gemm3(
    const short* __restrict__ A, const short* __restrict__ Bt,
    const float* __restrict__ bias, float* __restrict__ out) {
    __shared__ float tile[2][BM][68];      // 2 x 34,816 B
    int t = threadIdx.x;
    int w = t >> 6;
    int l = t & 63;
    int lr = l & 15;
    int lg = l >> 4;
    int mc = blockIdx.x >> 6;
    int c  = blockIdx.x & (N_CHAINS - 1);
    int nt0 = c * RUN_BASE + (c < RUN_EXTRA ? c : RUN_EXTRA);
    int cnt = RUN_BASE + (c < RUN_EXTRA ? 1 : 0);
    int m_base = mc * BM;

    short8 a[8][4];
#pragma unroll
    for (int mi = 0; mi < 8; ++mi) {
        const short* arow = A + (size_t)(m_base + mi * 16 + lr) * FIN + lg * 8;
#pragma unroll
        for (int ks = 0; ks < 4; ++ks) a[mi][ks] = *(const short8*)(arow + ks * 32);
    }

    const short* bbase = Bt + (size_t)(w * 16 + lr) * FIN + lg * 8;
    short8 b0[4], b1[4];
    {
        const short* p = bbase + (size_t)nt0 * 64 * FIN;
#pragma unroll
        for (int ks = 0; ks < 4; ++ks) b0[ks] = *(const short8*)(p + ks * 32);
    }

    int scol = lr * 4;
    int p = 0;

    for (int i = 0; i < cnt; ++i) {
        int nt = nt0 + i;
        if (i + 1 < cnt) {
            const short* pp = bbase + (size_t)(nt + 1) * 64 * FIN;
#pragma unroll
            for (int ks = 0; ks < 4; ++ks) b1[ks] = *(const short8*)(pp + ks * 32);
        }
#pragma unroll
        for (int mi = 0; mi < 8; ++mi) {
            f32x4 acc = {};
#pragma unroll
            for (int ks = 0; ks < 4; ++ks)
                acc = __builtin_amdgcn_mfma_f32_16x16x32_bf16(b0[ks], a[mi][ks], acc, 0, 0, 0);
            *(f32x4*)&tile[p][mi * 16 + lr][w * 16 + lg * 4] = acc;
        }
        __syncthreads();                   // single barrier per iteration
        {
            int gcol = nt * 64 + scol;
            bool ok = gcol < N_SERVICES;
            f32x4 bv = {};
            if (ok) bv = *(const f32x4*)&bias[gcol];
            float* ob = out + (size_t)m_base * N_SERVICES + gcol;
#pragma unroll
            for (int si = 0; si < 8; ++si) {
                int row = w * 32 + si * 4 + lg;
                f32x4 v = *(const f32x4*)&tile[p][row][scol] + bv;
                if (ok)
                    __builtin_nontemporal_store(
                        v, (f32x4*)(ob + (size_t)row * N_SERVICES));
            }
        }
        p ^= 1;
#pragma unroll
        for (int ks = 0; ks < 4; ++ks) b0[ks] = b1[ks];
    }
}

// ---------------- launch ----------------

extern "C" void kernel_launch(void* const* d_in, const int* in_sizes, int n_in,
                              void* d_out, int out_size, void* d_ws, size_t ws_size,
                              hipStream_t stream) {
    const int*   user_idx    = (const int*)d_in[0];
    const int*   ctx_idx     = (const int*)d_in[1];
    const int*   ei          = (const int*)d_in[2];
    const float* user_emb    = (const float*)d_in[3];
    const float* service_emb = (const float*)d_in[4];
    const float* W1          = (const float*)d_in[5];
    const float* b1          = (const float*)d_in[6];
    const float* W2          = (const float*)d_in[7];
    const float* b2          = (const float*)d_in[8];
    const float* fcW         = (const float*)d_in[9];
    const float* fcb         = (const float*)d_in[10];
    float* out = (float*)d_out;

    const int* src = ei;
    const int* dst = ei + N_EDGES;

    char* ws = (char*)d_ws;
    float*          dis       = (float*)(ws);                    // 200,000
    unsigned short* h1        = (unsigned short*)(ws + 200000);  // 3,200,000 (bf16 h1')
    unsigned short* h2b       = (unsigned short*)(ws + 3400000); // 3,200,000 (bf16 h2')
    float*          g         = (float*)(ws + 6600000);          // 6,400,000 (g2, ctx rows)
    unsigned short* partial   = (unsigned short*)(ws + 6600000); // 6,400,000 overlay (dead before k_agg_ctx)
    unsigned short* xb        = (unsigned short*)(ws + 13000000);//   524,288
    short*          Wt        = (short*)(ws + 13524288);         // 12,812,288
    int*            row_start = (int*)(ws + 26336576);           // 200,004
    int*            csr_src   = (int*)(ws + 26736580);           // 6,400,000
    int*            tmp       = (int*)(ws + 26736580);           // 200,000 overlay (dead before k_fill)
    int*            blocksum  = (int*)(ws + 33136580);           // 1,024
    int*            mask      = (int*)(ws + 33137604);           // 200,000
    int*            ctx_list  = (int*)(ws + 33337604);           // 24,576
    int*            ctx_count = (int*)(ws + 33362180);           // 4     (total ~33.4 MB)

    // cvtW also zeroes mask + ctx_count (runs first)
    k_cvtW<<<N_PAD / 32, 256, 0, stream>>>(fcW, Wt, mask, ctx_count);

    // CSR build — no global atomics, 448-block count/fill
    k_tiled_count<<<R_RANGES * C_CHUNKS, 256, 0, stream>>>(dst, partial);
    k_scan_block<<<196, 256, 0, stream>>>(partial, dis, tmp, blocksum);
    // fused: scan finish + ctx list + in-place chunk offsets ∥ layer-1 transform
    k_scanfin_tf<<<196 + 6250, 256, 0, stream>>>(tmp, blocksum, row_start,
                                                 ctx_idx, mask, ctx_list, ctx_count,
                                                 partial, service_emb, W1, dis, h1);
    k_fill<<<R_RANGES * C_CHUNKS, 256, 0, stream>>>(src, dst, row_start, partial, csr_src);

    // fused layer-1 agg + ReLU + layer-2 transform (g1 never leaves LDS)
    k_agg_tf<<<3125, 256, 0, stream>>>(row_start, csr_src, dis,
                                       (const unsigned int*)h1, b1, W2, h2b);
    // layer-2 agg over compact ctx list (g overlays partial — partial dead now)
    k_agg_ctx<<<N_CTX / 16, 256, 0, stream>>>(row_start, csr_src, dis,
                                              (const unsigned int*)h2b, b2,
                                              ctx_list, ctx_count, g);

    k_gather<<<BATCH * FIN / 256, 256, 0, stream>>>(user_idx, ctx_idx, user_emb, g, xb);

    k_gemm3<<<GEMM_BLKS, 256, 0, stream>>>((const short*)xb, Wt, fcb, out);
}

// Round 19
// 214.854 us; speedup vs baseline: 2.1673x; 1.0230x over previous
//
#include <hip/hip_runtime.h>

#define N_SERVICES 50000
#define N_PAD      50048   // 782*64
#define N_EDGES    1600000
#define N_CTX      6144    // BATCH*CONTEXT
#define EMB        32
#define BATCH      2048
#define FIN        128     // (CONTEXT+1)*EMB
#define N_TILES    782
#define BM         128
#define M_CHUNKS   16      // 2048 / BM
#define N_CHAINS   64
#define GEMM_BLKS  (M_CHUNKS * N_CHAINS)   // 1024
#define RUN_BASE   12      // 782 = 64*12 + 14
#define RUN_EXTRA  14

// --- tiled CSR build geometry ---
#define RANGE      8192                   // nodes per range (2^13)
#define R_RANGES   7                      // ceil(50000/8192)
#define C_CHUNKS   64
#define PSTR       50000                  // partial stride (nodes, ushort)
#define EPC        (N_EDGES / C_CHUNKS)   // 25000 edges/chunk
#define I4PC       (EPC / 4)              // 6250 int4/chunk
#define CVT_BLKS   (N_PAD / 32)           // 1564

typedef __attribute__((ext_vector_type(4))) float f32x4;
typedef __attribute__((ext_vector_type(2))) float f32x2;
typedef __attribute__((ext_vector_type(8))) short short8;

__device__ inline unsigned short f2bf(float f) {
    unsigned u = __float_as_uint(f);
    unsigned r = (u + 0x7FFFu + ((u >> 16) & 1u)) >> 16;
    return (unsigned short)r;
}
__device__ inline float bf2f(unsigned short b) {
    return __uint_as_float(((unsigned)b) << 16);
}

// ---------------- prep: fc_W cvt/transpose ∥ tiled count (merged launch) --------
// blocks [0,1564): cvtW. blocks [1564,2012): LDS-histogram count (no global atomics).

__global__ __launch_bounds__(256) void k_prep(const float* __restrict__ W,
                                              short* __restrict__ Wt,
                                              const int* __restrict__ dst,
                                              unsigned short* __restrict__ partial) {
    __shared__ __align__(16) char smem[32768];
    int t = threadIdx.x;

    if (blockIdx.x < CVT_BLKS) {
        short (*lds)[33] = (short(*)[33])smem;
        int n0 = blockIdx.x * 32;
        int nx = t & 31;
        int n  = n0 + nx;
        int kg = t >> 5;                 // 0..7
#pragma unroll
        for (int r = 0; r < 16; ++r) {
            int k = r * 8 + kg;
            float v = (n < N_SERVICES) ? W[k * N_SERVICES + n] : 0.f;
            lds[k][nx] = (short)f2bf(v);
        }
        __syncthreads();
        int nr = t >> 3;                 // 0..31
        int kc = (t & 7) * 16;
        short tmpv[16];
#pragma unroll
        for (int i = 0; i < 16; ++i) tmpv[i] = lds[kc + i][nr];
        short8* dstp = (short8*)(Wt + (size_t)(n0 + nr) * FIN + kc);
        dstp[0] = *(short8*)&tmpv[0];
        dstp[1] = *(short8*)&tmpv[8];
    } else {
        int* hist = (int*)smem;
        int bid = blockIdx.x - CVT_BLKS;
        int r = bid / C_CHUNKS;
        int c = bid % C_CHUNKS;
        for (int i = t; i < RANGE; i += 256) hist[i] = 0;
        __syncthreads();
        const int4* d4 = (const int4*)(dst + c * EPC);
        for (int i = t; i < I4PC; i += 256) {
            int4 d = d4[i];
            if ((d.x >> 13) == r) atomicAdd(&hist[d.x & (RANGE - 1)], 1);
            if ((d.y >> 13) == r) atomicAdd(&hist[d.y & (RANGE - 1)], 1);
            if ((d.z >> 13) == r) atomicAdd(&hist[d.z & (RANGE - 1)], 1);
            if ((d.w >> 13) == r) atomicAdd(&hist[d.w & (RANGE - 1)], 1);
        }
        __syncthreads();
        int base = r * RANGE;
        unsigned short* p = partial + (size_t)c * PSTR;
        for (int i = t; i < RANGE; i += 256) {
            int n = base + i;
            if (n < N_SERVICES) p[n] = (unsigned short)hist[i];
        }
    }
}

// ---------------- scan pass 1; chunk-reduce + dis folded in ----------------

__global__ void k_scan_block(const unsigned short* __restrict__ partial,
                             float* __restrict__ dis,
                             int* __restrict__ tmp, int* __restrict__ blocksum) {
    __shared__ int s[256];
    int t = threadIdx.x, i = blockIdx.x * 256 + t;
    int v = 0;
    if (i < N_SERVICES) {
#pragma unroll 8
        for (int c = 0; c < C_CHUNKS; ++c) v += partial[(size_t)c * PSTR + i];
        dis[i] = rsqrtf((float)(v + 1));  // +1 self-loop
    }
    s[t] = v;
    __syncthreads();
#pragma unroll
    for (int o = 1; o < 256; o <<= 1) {
        int x = 0;
        if (t >= o) x = s[t - o];
        __syncthreads();
        if (t >= o) s[t] += x;
        __syncthreads();
    }
    if (i < N_SERVICES) tmp[i] = s[t] - v;       // exclusive within block
    if (t == 255) blocksum[blockIdx.x] = s[255];
}

// ---------------- fused: scan finish + IN-PLACE chunk offsets ∥ transform -------
// blocks 0..195: finish row_start, convert partial counts -> exclusive per-node
// chunk offsets (in place, ushort). blocks 196..6445: h1' = (emb @ W1)*dis.

__global__ __launch_bounds__(256) void k_scanfin_tf(
    const int* __restrict__ tmp, const int* __restrict__ blocksum,
    int* __restrict__ row_start,
    unsigned short* __restrict__ partial,
    const float* __restrict__ in, const float* __restrict__ W1,
    const float* __restrict__ dis, unsigned short* __restrict__ h) {
    __shared__ int s[256];
    __shared__ float Ws[EMB][EMB + 1];
    __shared__ float rows[8][EMB];
    int t = threadIdx.x;

    if (blockIdx.x < 196) {
        int v = (t < 196) ? blocksum[t] : 0;
        s[t] = v;
        __syncthreads();
#pragma unroll
        for (int o = 1; o < 256; o <<= 1) {
            int x = 0;
            if (t >= o) x = s[t - o];
            __syncthreads();
            if (t >= o) s[t] += x;
            __syncthreads();
        }
        int prefix = (blockIdx.x == 0) ? 0 : s[blockIdx.x - 1];
        int i = blockIdx.x * 256 + t;
        if (i < N_SERVICES) {
            row_start[i] = tmp[i] + prefix;
            int acc = 0;
#pragma unroll 8
            for (int c = 0; c < C_CHUNKS; ++c) {
                size_t idx = (size_t)c * PSTR + i;
                int cnt = partial[idx];
                partial[idx] = (unsigned short)acc;
                acc += cnt;
            }
        }
        if (i == 0) row_start[N_SERVICES] = N_EDGES;
    } else {
        int j = t & 31, li = t >> 5;
        for (int i = t; i < EMB * EMB; i += 256) Ws[i >> 5][i & 31] = W1[i];
        int node = (blockIdx.x - 196) * 8 + li;
        if (node < N_SERVICES) rows[li][j] = in[node * EMB + j];
        __syncthreads();
        if (node < N_SERVICES) {
            float acc = 0.f;
#pragma unroll
            for (int k = 0; k < EMB; ++k) acc = fmaf(rows[li][k], Ws[k][j], acc);
            h[node * EMB + j] = f2bf(acc * dis[node]);
        }
    }
}

// ---------------- fill: LDS cursors from row_start + in-place offsets ----------

__global__ __launch_bounds__(256) void k_fill(const int* __restrict__ src,
                                              const int* __restrict__ dst,
                                              const int* __restrict__ row_start,
                                              const unsigned short* __restrict__ partial,
                                              int* __restrict__ csr_src) {
    __shared__ int cur[RANGE];
    int t = threadIdx.x;
    int r = blockIdx.x / C_CHUNKS;
    int c = blockIdx.x % C_CHUNKS;
    int base = r * RANGE;
    const unsigned short* off = partial + (size_t)c * PSTR;
    for (int i = t; i < RANGE; i += 256) {
        int n = base + i;
        cur[i] = (n < N_SERVICES) ? (row_start[n] + off[n]) : 0;
    }
    __syncthreads();
    const int4* d4 = (const int4*)(dst + c * EPC);
    const int4* s4 = (const int4*)(src + c * EPC);
    for (int i = t; i < I4PC; i += 256) {
        int4 d = d4[i];
        int4 s = s4[i];
        if ((d.x >> 13) == r) csr_src[atomicAdd(&cur[d.x & (RANGE - 1)], 1)] = s.x;
        if ((d.y >> 13) == r) csr_src[atomicAdd(&cur[d.y & (RANGE - 1)], 1)] = s.y;
        if ((d.z >> 13) == r) csr_src[atomicAdd(&cur[d.z & (RANGE - 1)], 1)] = s.z;
        if ((d.w >> 13) == r) csr_src[atomicAdd(&cur[d.w & (RANGE - 1)], 1)] = s.w;
    }
}

// ---------------- fused layer-1 agg + ReLU + layer-2 transform ----------------

__global__ __launch_bounds__(256) void k_agg_tf(
    const int* __restrict__ row_start, const int* __restrict__ csr_src,
    const float* __restrict__ dis, const unsigned int* __restrict__ h2,
    const float* __restrict__ b, const float* __restrict__ W2,
    unsigned short* __restrict__ hout) {
    __shared__ float gr[16][33];
    __shared__ float Ws[32][33];
    int t = threadIdx.x;
    for (int i = t; i < EMB * EMB; i += 256) Ws[i >> 5][i & 31] = W2[i];

    int j2 = t & 15;                       // dim pair
    int local = t >> 4;
    int node = blockIdx.x * 16 + local;
    int e = row_start[node], e1 = row_start[node + 1];
    float al0 = 0.f, ah0 = 0.f, al1 = 0.f, ah1 = 0.f;
    float al2 = 0.f, ah2 = 0.f, al3 = 0.f, ah3 = 0.f;
    for (; e + 4 <= e1; e += 4) {
        int s0 = csr_src[e], s1 = csr_src[e + 1], s2 = csr_src[e + 2], s3 = csr_src[e + 3];
        unsigned v0 = h2[s0 * 16 + j2], v1 = h2[s1 * 16 + j2];
        unsigned v2 = h2[s2 * 16 + j2], v3 = h2[s3 * 16 + j2];
        al0 += bf2f((unsigned short)(v0 & 0xffff)); ah0 += bf2f((unsigned short)(v0 >> 16));
        al1 += bf2f((unsigned short)(v1 & 0xffff)); ah1 += bf2f((unsigned short)(v1 >> 16));
        al2 += bf2f((unsigned short)(v2 & 0xffff)); ah2 += bf2f((unsigned short)(v2 >> 16));
        al3 += bf2f((unsigned short)(v3 & 0xffff)); ah3 += bf2f((unsigned short)(v3 >> 16));
    }
    for (; e < e1; ++e) {
        unsigned v0 = h2[csr_src[e] * 16 + j2];
        al0 += bf2f((unsigned short)(v0 & 0xffff)); ah0 += bf2f((unsigned short)(v0 >> 16));
    }
    float dn = dis[node];
    unsigned vn = h2[node * 16 + j2];
    float lo = dn * ((al0 + al1) + (al2 + al3) + bf2f((unsigned short)(vn & 0xffff))) + b[j2 * 2];
    float hi = dn * ((ah0 + ah1) + (ah2 + ah3) + bf2f((unsigned short)(vn >> 16))) + b[j2 * 2 + 1];
    gr[local][j2 * 2]     = fmaxf(lo, 0.f);
    gr[local][j2 * 2 + 1] = fmaxf(hi, 0.f);
    __syncthreads();

    int d = t & 31;
    int l0 = t >> 5;                       // 0..7
    float s0 = 0.f, s1 = 0.f;
#pragma unroll
    for (int k = 0; k < EMB; ++k) {
        float w = Ws[k][d];
        s0 = fmaf(gr[l0][k], w, s0);
        s1 = fmaf(gr[l0 + 8][k], w, s1);
    }
    int n0 = blockIdx.x * 16 + l0;
    hout[(size_t)n0 * EMB + d]       = f2bf(s0 * dis[n0]);
    hout[(size_t)(n0 + 8) * EMB + d] = f2bf(s1 * dis[n0 + 8]);
}

// ---------------- layer-2 agg (slot-parallel) + user gather -> xb direct --------
// 512 blocks x 16 units = 8192: units [0,6144) = ctx slots (dups recomputed,
// identical values -> disjoint xb slots, no dedup needed); [6144,8192) = user rows.

__global__ void k_agg_gather(const int* __restrict__ row_start, const int* __restrict__ csr_src,
                             const float* __restrict__ dis, const unsigned int* __restrict__ h2,
                             const float* __restrict__ b,
                             const int* __restrict__ user_idx, const int* __restrict__ ctx_idx,
                             const float* __restrict__ user_emb,
                             unsigned short* __restrict__ xb) {
    int t = threadIdx.x;
    int j2 = t & 15;
    int u = blockIdx.x * 16 + (t >> 4);
    if (u < N_CTX) {
        int bb = u / 3, cc = u - bb * 3;
        int node = ctx_idx[u];
        int e = row_start[node], e1 = row_start[node + 1];
        float al0 = 0.f, ah0 = 0.f, al1 = 0.f, ah1 = 0.f;
        float al2 = 0.f, ah2 = 0.f, al3 = 0.f, ah3 = 0.f;
        for (; e + 4 <= e1; e += 4) {
            int s0 = csr_src[e], s1 = csr_src[e + 1], s2 = csr_src[e + 2], s3 = csr_src[e + 3];
            unsigned v0 = h2[s0 * 16 + j2], v1 = h2[s1 * 16 + j2];
            unsigned v2 = h2[s2 * 16 + j2], v3 = h2[s3 * 16 + j2];
            al0 += bf2f((unsigned short)(v0 & 0xffff)); ah0 += bf2f((unsigned short)(v0 >> 16));
            al1 += bf2f((unsigned short)(v1 & 0xffff)); ah1 += bf2f((unsigned short)(v1 >> 16));
            al2 += bf2f((unsigned short)(v2 & 0xffff)); ah2 += bf2f((unsigned short)(v2 >> 16));
            al3 += bf2f((unsigned short)(v3 & 0xffff)); ah3 += bf2f((unsigned short)(v3 >> 16));
        }
        for (; e < e1; ++e) {
            unsigned v0 = h2[csr_src[e] * 16 + j2];
            al0 += bf2f((unsigned short)(v0 & 0xffff)); ah0 += bf2f((unsigned short)(v0 >> 16));
        }
        float dn = dis[node];
        unsigned vn = h2[node * 16 + j2];
        float lo = dn * ((al0 + al1) + (al2 + al3) + bf2f((unsigned short)(vn & 0xffff))) + b[j2 * 2];
        float hi = dn * ((ah0 + ah1) + (ah2 + ah3) + bf2f((unsigned short)(vn >> 16))) + b[j2 * 2 + 1];
        ushort2 o;
        o.x = f2bf(lo);
        o.y = f2bf(hi);
        *(ushort2*)&xb[(size_t)bb * FIN + EMB + cc * EMB + j2 * 2] = o;
    } else {
        int bb = u - N_CTX;
        f32x2 v = *(const f32x2*)&user_emb[(size_t)user_idx[bb] * EMB + j2 * 2];
        ushort2 o;
        o.x = f2bf(v.x);
        o.y = f2bf(v.y);
        *(ushort2*)&xb[(size_t)bb * FIN + j2 * 2] = o;
    }
}

// ---------------- final GEMM: r12-exact (dbuf LDS, NT stores) ----------------

__global__ __launch_bounds__(256, 2) void k_gemm3(
    const short* __restrict__ A, const short* __restrict__ Bt,
    const float* __restrict__ bias, float* __restrict__ out) {
    __shared__ float tile[2][BM][68];      // 2 x 34,816 B
    int t = threadIdx.x;
    int w = t >> 6;
    int l = t & 63;
    int lr = l & 15;
    int lg = l >> 4;
    int mc = blockIdx.x >> 6;
    int c  = blockIdx.x & (N_CHAINS - 1);
    int nt0 = c * RUN_BASE + (c < RUN_EXTRA ? c : RUN_EXTRA);
    int cnt = RUN_BASE + (c < RUN_EXTRA ? 1 : 0);
    int m_base = mc * BM;

    short8 a[8][4];
#pragma unroll
    for (int mi = 0; mi < 8; ++mi) {
        const short* arow = A + (size_t)(m_base + mi * 16 + lr) * FIN + lg * 8;
#pragma unroll
        for (int ks = 0; ks < 4; ++ks) a[mi][ks] = *(const short8*)(arow + ks * 32);
    }

    const short* bbase = Bt + (size_t)(w * 16 + lr) * FIN + lg * 8;
    short8 b0[4], b1[4];
    {
        const short* p = bbase + (size_t)nt0 * 64 * FIN;
#pragma unroll
        for (int ks = 0; ks < 4; ++ks) b0[ks] = *(const short8*)(p + ks * 32);
    }

    int scol = lr * 4;
    int p = 0;

    for (int i = 0; i < cnt; ++i) {
        int nt = nt0 + i;
        if (i + 1 < cnt) {
            const short* pp = bbase + (size_t)(nt + 1) * 64 * FIN;
#pragma unroll
            for (int ks = 0; ks < 4; ++ks) b1[ks] = *(const short8*)(pp + ks * 32);
        }
#pragma unroll
        for (int mi = 0; mi < 8; ++mi) {
            f32x4 acc = {};
#pragma unroll
            for (int ks = 0; ks < 4; ++ks)
                acc = __builtin_amdgcn_mfma_f32_16x16x32_bf16(b0[ks], a[mi][ks], acc, 0, 0, 0);
            *(f32x4*)&tile[p][mi * 16 + lr][w * 16 + lg * 4] = acc;
        }
        __syncthreads();                   // single barrier per iteration
        {
            int gcol = nt * 64 + scol;
            bool ok = gcol < N_SERVICES;
            f32x4 bv = {};
            if (ok) bv = *(const f32x4*)&bias[gcol];
            float* ob = out + (size_t)m_base * N_SERVICES + gcol;
#pragma unroll
            for (int si = 0; si < 8; ++si) {
                int row = w * 32 + si * 4 + lg;
                f32x4 v = *(const f32x4*)&tile[p][row][scol] + bv;
                if (ok)
                    __builtin_nontemporal_store(
                        v, (f32x4*)(ob + (size_t)row * N_SERVICES));
            }
        }
        p ^= 1;
#pragma unroll
        for (int ks = 0; ks < 4; ++ks) b0[ks] = b1[ks];
    }
}

// ---------------- launch ----------------

extern "C" void kernel_launch(void* const* d_in, const int* in_sizes, int n_in,
                              void* d_out, int out_size, void* d_ws, size_t ws_size,
                              hipStream_t stream) {
    const int*   user_idx    = (const int*)d_in[0];
    const int*   ctx_idx     = (const int*)d_in[1];
    const int*   ei          = (const int*)d_in[2];
    const float* user_emb    = (const float*)d_in[3];
    const float* service_emb = (const float*)d_in[4];
    const float* W1          = (const float*)d_in[5];
    const float* b1          = (const float*)d_in[6];
    const float* W2          = (const float*)d_in[7];
    const float* b2          = (const float*)d_in[8];
    const float* fcW         = (const float*)d_in[9];
    const float* fcb         = (const float*)d_in[10];
    float* out = (float*)d_out;

    const int* src = ei;
    const int* dst = ei + N_EDGES;

    char* ws = (char*)d_ws;
    float*          dis       = (float*)(ws);                    // 200,000
    unsigned short* h1        = (unsigned short*)(ws + 200000);  // 3,200,000 (bf16 h1')
    unsigned short* h2b       = (unsigned short*)(ws + 3400000); // 3,200,000 (bf16 h2')
    unsigned short* partial   = (unsigned short*)(ws + 6600000); // 6,400,000
    unsigned short* xb        = (unsigned short*)(ws + 13000000);//   524,288
    short*          Wt        = (short*)(ws + 13524288);         // 12,812,288
    int*            row_start = (int*)(ws + 26336576);           // 200,004
    int*            csr_src   = (int*)(ws + 26736580);           // 6,400,000
    int*            tmp       = (int*)(ws + 26736580);           // 200,000 overlay (dead before k_fill)
    int*            blocksum  = (int*)(ws + 33136580);           // 1,024  (total ~33.1 MB)

    // cvtW ∥ tiled count (merged)
    k_prep<<<CVT_BLKS + R_RANGES * C_CHUNKS, 256, 0, stream>>>(fcW, Wt, dst, partial);
    k_scan_block<<<196, 256, 0, stream>>>(partial, dis, tmp, blocksum);
    // fused: scan finish + in-place chunk offsets ∥ layer-1 transform
    k_scanfin_tf<<<196 + 6250, 256, 0, stream>>>(tmp, blocksum, row_start,
                                                 partial, service_emb, W1, dis, h1);
    k_fill<<<R_RANGES * C_CHUNKS, 256, 0, stream>>>(src, dst, row_start, partial, csr_src);

    // fused layer-1 agg + ReLU + layer-2 transform (g1 never leaves LDS)
    k_agg_tf<<<3125, 256, 0, stream>>>(row_start, csr_src, dis,
                                       (const unsigned int*)h1, b1, W2, h2b);
    // layer-2 agg (slot-parallel) + user gather -> xb (bf16), no dedup/g buffer
    k_agg_gather<<<512, 256, 0, stream>>>(row_start, csr_src, dis,
                                          (const unsigned int*)h2b, b2,
                                          user_idx, ctx_idx, user_emb, xb);

    k_gemm3<<<GEMM_BLKS, 256, 0, stream>>>((const short*)xb, Wt, fcb, out);
}

// Round 20
// 214.002 us; speedup vs baseline: 2.1759x; 1.0040x over previous
//
#include <hip/hip_runtime.h>

#define N_SERVICES 50000
#define N_PAD      50048   // 782*64
#define N_EDGES    1600000
#define N_CTX      6144    // BATCH*CONTEXT
#define EMB        32
#define BATCH      2048
#define FIN        128     // (CONTEXT+1)*EMB
#define N_TILES    782
#define BM         128
#define M_CHUNKS   16      // 2048 / BM
#define N_CHAINS   64
#define GEMM_BLKS  (M_CHUNKS * N_CHAINS)   // 1024

// --- tiled CSR build geometry ---
#define RANGE      8192                   // nodes per range (2^13)
#define R_RANGES   7                      // ceil(50000/8192)
#define C_CHUNKS   64
#define PSTR       50000                  // partial stride (nodes, ushort)
#define EPC        (N_EDGES / C_CHUNKS)   // 25000 edges/chunk
#define I4PC       (EPC / 4)              // 6250 int4/chunk
#define CVT_BLKS   (N_PAD / 32)           // 1564

typedef __attribute__((ext_vector_type(4))) float f32x4;
typedef __attribute__((ext_vector_type(2))) float f32x2;
typedef __attribute__((ext_vector_type(8))) short short8;

__device__ inline unsigned short f2bf(float f) {
    unsigned u = __float_as_uint(f);
    unsigned r = (u + 0x7FFFu + ((u >> 16) & 1u)) >> 16;
    return (unsigned short)r;
}
__device__ inline float bf2f(unsigned short b) {
    return __uint_as_float(((unsigned)b) << 16);
}

// ---------------- prep: fc_W cvt/transpose ∥ tiled count (merged launch) --------

__global__ __launch_bounds__(256) void k_prep(const float* __restrict__ W,
                                              short* __restrict__ Wt,
                                              const int* __restrict__ dst,
                                              unsigned short* __restrict__ partial) {
    __shared__ __align__(16) char smem[32768];
    int t = threadIdx.x;

    if (blockIdx.x < CVT_BLKS) {
        short (*lds)[33] = (short(*)[33])smem;
        int n0 = blockIdx.x * 32;
        int nx = t & 31;
        int n  = n0 + nx;
        int kg = t >> 5;                 // 0..7
#pragma unroll
        for (int r = 0; r < 16; ++r) {
            int k = r * 8 + kg;
            float v = (n < N_SERVICES) ? W[k * N_SERVICES + n] : 0.f;
            lds[k][nx] = (short)f2bf(v);
        }
        __syncthreads();
        int nr = t >> 3;                 // 0..31
        int kc = (t & 7) * 16;
        short tmpv[16];
#pragma unroll
        for (int i = 0; i < 16; ++i) tmpv[i] = lds[kc + i][nr];
        short8* dstp = (short8*)(Wt + (size_t)(n0 + nr) * FIN + kc);
        dstp[0] = *(short8*)&tmpv[0];
        dstp[1] = *(short8*)&tmpv[8];
    } else {
        int* hist = (int*)smem;
        int bid = blockIdx.x - CVT_BLKS;
        int r = bid / C_CHUNKS;
        int c = bid % C_CHUNKS;
        for (int i = t; i < RANGE; i += 256) hist[i] = 0;
        __syncthreads();
        const int4* d4 = (const int4*)(dst + c * EPC);
        for (int i = t; i < I4PC; i += 256) {
            int4 d = d4[i];
            if ((d.x >> 13) == r) atomicAdd(&hist[d.x & (RANGE - 1)], 1);
            if ((d.y >> 13) == r) atomicAdd(&hist[d.y & (RANGE - 1)], 1);
            if ((d.z >> 13) == r) atomicAdd(&hist[d.z & (RANGE - 1)], 1);
            if ((d.w >> 13) == r) atomicAdd(&hist[d.w & (RANGE - 1)], 1);
        }
        __syncthreads();
        int base = r * RANGE;
        unsigned short* p = partial + (size_t)c * PSTR;
        for (int i = t; i < RANGE; i += 256) {
            int n = base + i;
            if (n < N_SERVICES) p[n] = (unsigned short)hist[i];
        }
    }
}

// ---------------- scan pass 1; chunk-reduce + dis folded in ----------------

__global__ void k_scan_block(const unsigned short* __restrict__ partial,
                             float* __restrict__ dis,
                             int* __restrict__ tmp, int* __restrict__ blocksum) {
    __shared__ int s[256];
    int t = threadIdx.x, i = blockIdx.x * 256 + t;
    int v = 0;
    if (i < N_SERVICES) {
#pragma unroll 8
        for (int c = 0; c < C_CHUNKS; ++c) v += partial[(size_t)c * PSTR + i];
        dis[i] = rsqrtf((float)(v + 1));  // +1 self-loop
    }
    s[t] = v;
    __syncthreads();
#pragma unroll
    for (int o = 1; o < 256; o <<= 1) {
        int x = 0;
        if (t >= o) x = s[t - o];
        __syncthreads();
        if (t >= o) s[t] += x;
        __syncthreads();
    }
    if (i < N_SERVICES) tmp[i] = s[t] - v;       // exclusive within block
    if (t == 255) blocksum[blockIdx.x] = s[255];
}

// ---------------- fused: scan finish + IN-PLACE chunk offsets ∥ transform -------

__global__ __launch_bounds__(256) void k_scanfin_tf(
    const int* __restrict__ tmp, const int* __restrict__ blocksum,
    int* __restrict__ row_start,
    unsigned short* __restrict__ partial,
    const float* __restrict__ in, const float* __restrict__ W1,
    const float* __restrict__ dis, unsigned short* __restrict__ h) {
    __shared__ int s[256];
    __shared__ float Ws[EMB][EMB + 1];
    __shared__ float rows[8][EMB];
    int t = threadIdx.x;

    if (blockIdx.x < 196) {
        int v = (t < 196) ? blocksum[t] : 0;
        s[t] = v;
        __syncthreads();
#pragma unroll
        for (int o = 1; o < 256; o <<= 1) {
            int x = 0;
            if (t >= o) x = s[t - o];
            __syncthreads();
            if (t >= o) s[t] += x;
            __syncthreads();
        }
        int prefix = (blockIdx.x == 0) ? 0 : s[blockIdx.x - 1];
        int i = blockIdx.x * 256 + t;
        if (i < N_SERVICES) {
            row_start[i] = tmp[i] + prefix;
            int acc = 0;
#pragma unroll 8
            for (int c = 0; c < C_CHUNKS; ++c) {
                size_t idx = (size_t)c * PSTR + i;
                int cnt = partial[idx];
                partial[idx] = (unsigned short)acc;
                acc += cnt;
            }
        }
        if (i == 0) row_start[N_SERVICES] = N_EDGES;
    } else {
        int j = t & 31, li = t >> 5;
        for (int i = t; i < EMB * EMB; i += 256) Ws[i >> 5][i & 31] = W1[i];
        int node = (blockIdx.x - 196) * 8 + li;
        if (node < N_SERVICES) rows[li][j] = in[node * EMB + j];
        __syncthreads();
        if (node < N_SERVICES) {
            float acc = 0.f;
#pragma unroll
            for (int k = 0; k < EMB; ++k) acc = fmaf(rows[li][k], Ws[k][j], acc);
            h[node * EMB + j] = f2bf(acc * dis[node]);
        }
    }
}

// ---------------- fill: LDS cursors from row_start + in-place offsets ----------

__global__ __launch_bounds__(256) void k_fill(const int* __restrict__ src,
                                              const int* __restrict__ dst,
                                              const int* __restrict__ row_start,
                                              const unsigned short* __restrict__ partial,
                                              int* __restrict__ csr_src) {
    __shared__ int cur[RANGE];
    int t = threadIdx.x;
    int r = blockIdx.x / C_CHUNKS;
    int c = blockIdx.x % C_CHUNKS;
    int base = r * RANGE;
    const unsigned short* off = partial + (size_t)c * PSTR;
    for (int i = t; i < RANGE; i += 256) {
        int n = base + i;
        cur[i] = (n < N_SERVICES) ? (row_start[n] + off[n]) : 0;
    }
    __syncthreads();
    const int4* d4 = (const int4*)(dst + c * EPC);
    const int4* s4 = (const int4*)(src + c * EPC);
    for (int i = t; i < I4PC; i += 256) {
        int4 d = d4[i];
        int4 s = s4[i];
        if ((d.x >> 13) == r) csr_src[atomicAdd(&cur[d.x & (RANGE - 1)], 1)] = s.x;
        if ((d.y >> 13) == r) csr_src[atomicAdd(&cur[d.y & (RANGE - 1)], 1)] = s.y;
        if ((d.z >> 13) == r) csr_src[atomicAdd(&cur[d.z & (RANGE - 1)], 1)] = s.z;
        if ((d.w >> 13) == r) csr_src[atomicAdd(&cur[d.w & (RANGE - 1)], 1)] = s.w;
    }
}

// ---------------- fused layer-1 agg + ReLU + layer-2 transform ----------------

__global__ __launch_bounds__(256) void k_agg_tf(
    const int* __restrict__ row_start, const int* __restrict__ csr_src,
    const float* __restrict__ dis, const unsigned int* __restrict__ h2,
    const float* __restrict__ b, const float* __restrict__ W2,
    unsigned short* __restrict__ hout) {
    __shared__ float gr[16][33];
    __shared__ float Ws[32][33];
    int t = threadIdx.x;
    for (int i = t; i < EMB * EMB; i += 256) Ws[i >> 5][i & 31] = W2[i];

    int j2 = t & 15;                       // dim pair
    int local = t >> 4;
    int node = blockIdx.x * 16 + local;
    int e = row_start[node], e1 = row_start[node + 1];
    float al0 = 0.f, ah0 = 0.f, al1 = 0.f, ah1 = 0.f;
    float al2 = 0.f, ah2 = 0.f, al3 = 0.f, ah3 = 0.f;
    for (; e + 4 <= e1; e += 4) {
        int s0 = csr_src[e], s1 = csr_src[e + 1], s2 = csr_src[e + 2], s3 = csr_src[e + 3];
        unsigned v0 = h2[s0 * 16 + j2], v1 = h2[s1 * 16 + j2];
        unsigned v2 = h2[s2 * 16 + j2], v3 = h2[s3 * 16 + j2];
        al0 += bf2f((unsigned short)(v0 & 0xffff)); ah0 += bf2f((unsigned short)(v0 >> 16));
        al1 += bf2f((unsigned short)(v1 & 0xffff)); ah1 += bf2f((unsigned short)(v1 >> 16));
        al2 += bf2f((unsigned short)(v2 & 0xffff)); ah2 += bf2f((unsigned short)(v2 >> 16));
        al3 += bf2f((unsigned short)(v3 & 0xffff)); ah3 += bf2f((unsigned short)(v3 >> 16));
    }
    for (; e < e1; ++e) {
        unsigned v0 = h2[csr_src[e] * 16 + j2];
        al0 += bf2f((unsigned short)(v0 & 0xffff)); ah0 += bf2f((unsigned short)(v0 >> 16));
    }
    float dn = dis[node];
    unsigned vn = h2[node * 16 + j2];
    float lo = dn * ((al0 + al1) + (al2 + al3) + bf2f((unsigned short)(vn & 0xffff))) + b[j2 * 2];
    float hi = dn * ((ah0 + ah1) + (ah2 + ah3) + bf2f((unsigned short)(vn >> 16))) + b[j2 * 2 + 1];
    gr[local][j2 * 2]     = fmaxf(lo, 0.f);
    gr[local][j2 * 2 + 1] = fmaxf(hi, 0.f);
    __syncthreads();

    int d = t & 31;
    int l0 = t >> 5;                       // 0..7
    float s0 = 0.f, s1 = 0.f;
#pragma unroll
    for (int k = 0; k < EMB; ++k) {
        float w = Ws[k][d];
        s0 = fmaf(gr[l0][k], w, s0);
        s1 = fmaf(gr[l0 + 8][k], w, s1);
    }
    int n0 = blockIdx.x * 16 + l0;
    hout[(size_t)n0 * EMB + d]       = f2bf(s0 * dis[n0]);
    hout[(size_t)(n0 + 8) * EMB + d] = f2bf(s1 * dis[n0 + 8]);
}

// ---------------- layer-2 agg (slot-parallel) + user gather -> xb direct --------

__global__ void k_agg_gather(const int* __restrict__ row_start, const int* __restrict__ csr_src,
                             const float* __restrict__ dis, const unsigned int* __restrict__ h2,
                             const float* __restrict__ b,
                             const int* __restrict__ user_idx, const int* __restrict__ ctx_idx,
                             const float* __restrict__ user_emb,
                             unsigned short* __restrict__ xb) {
    int t = threadIdx.x;
    int j2 = t & 15;
    int u = blockIdx.x * 16 + (t >> 4);
    if (u < N_CTX) {
        int bb = u / 3, cc = u - bb * 3;
        int node = ctx_idx[u];
        int e = row_start[node], e1 = row_start[node + 1];
        float al0 = 0.f, ah0 = 0.f, al1 = 0.f, ah1 = 0.f;
        float al2 = 0.f, ah2 = 0.f, al3 = 0.f, ah3 = 0.f;
        for (; e + 4 <= e1; e += 4) {
            int s0 = csr_src[e], s1 = csr_src[e + 1], s2 = csr_src[e + 2], s3 = csr_src[e + 3];
            unsigned v0 = h2[s0 * 16 + j2], v1 = h2[s1 * 16 + j2];
            unsigned v2 = h2[s2 * 16 + j2], v3 = h2[s3 * 16 + j2];
            al0 += bf2f((unsigned short)(v0 & 0xffff)); ah0 += bf2f((unsigned short)(v0 >> 16));
            al1 += bf2f((unsigned short)(v1 & 0xffff)); ah1 += bf2f((unsigned short)(v1 >> 16));
            al2 += bf2f((unsigned short)(v2 & 0xffff)); ah2 += bf2f((unsigned short)(v2 >> 16));
            al3 += bf2f((unsigned short)(v3 & 0xffff)); ah3 += bf2f((unsigned short)(v3 >> 16));
        }
        for (; e < e1; ++e) {
            unsigned v0 = h2[csr_src[e] * 16 + j2];
            al0 += bf2f((unsigned short)(v0 & 0xffff)); ah0 += bf2f((unsigned short)(v0 >> 16));
        }
        float dn = dis[node];
        unsigned vn = h2[node * 16 + j2];
        float lo = dn * ((al0 + al1) + (al2 + al3) + bf2f((unsigned short)(vn & 0xffff))) + b[j2 * 2];
        float hi = dn * ((ah0 + ah1) + (ah2 + ah3) + bf2f((unsigned short)(vn >> 16))) + b[j2 * 2 + 1];
        ushort2 o;
        o.x = f2bf(lo);
        o.y = f2bf(hi);
        *(ushort2*)&xb[(size_t)bb * FIN + EMB + cc * EMB + j2 * 2] = o;
    } else {
        int bb = u - N_CTX;
        f32x2 v = *(const f32x2*)&user_emb[(size_t)user_idx[bb] * EMB + j2 * 2];
        ushort2 o;
        o.x = f2bf(v.x);
        o.y = f2bf(v.y);
        *(ushort2*)&xb[(size_t)bb * FIN + j2 * 2] = o;
    }
}

// ---------------- final GEMM: INTERLEAVED chains (dense concurrent write band) --
// Chain c takes tiles c, c+64, c+128, ...: at step i all 64 chains write the SAME
// 4096-col band -> concurrent footprint = 2048 x 16KB dense streams instead of
// 131K x 256B scattered (page-locality theory; 5th and last write-cap lever).
// B-sharing/XCD map unchanged (bid%8 = c%8). dbuf LDS + NT stores as r12.

__global__ __launch_bounds__(256, 2) void k_gemm3(
    const short* __restrict__ A, const short* __restrict__ Bt,
    const float* __restrict__ bias, float* __restrict__ out) {
    __shared__ float tile[2][BM][68];      // 2 x 34,816 B
    int t = threadIdx.x;
    int w = t >> 6;
    int l = t & 63;
    int lr = l & 15;
    int lg = l >> 4;
    int mc = blockIdx.x >> 6;
    int c  = blockIdx.x & (N_CHAINS - 1);
    int m_base = mc * BM;

    short8 a[8][4];
#pragma unroll
    for (int mi = 0; mi < 8; ++mi) {
        const short* arow = A + (size_t)(m_base + mi * 16 + lr) * FIN + lg * 8;
#pragma unroll
        for (int ks = 0; ks < 4; ++ks) a[mi][ks] = *(const short8*)(arow + ks * 32);
    }

    const short* bbase = Bt + (size_t)(w * 16 + lr) * FIN + lg * 8;
    short8 b0[4], b1[4];
    {
        const short* p = bbase + (size_t)c * 64 * FIN;
#pragma unroll
        for (int ks = 0; ks < 4; ++ks) b0[ks] = *(const short8*)(p + ks * 32);
    }

    int scol = lr * 4;
    int p = 0;

    for (int nt = c; nt < N_TILES; nt += N_CHAINS) {
        int ntn = nt + N_CHAINS;
        if (ntn < N_TILES) {
            const short* pp = bbase + (size_t)ntn * 64 * FIN;
#pragma unroll
            for (int ks = 0; ks < 4; ++ks) b1[ks] = *(const short8*)(pp + ks * 32);
        }
#pragma unroll
        for (int mi = 0; mi < 8; ++mi) {
            f32x4 acc = {};
#pragma unroll
            for (int ks = 0; ks < 4; ++ks)
                acc = __builtin_amdgcn_mfma_f32_16x16x32_bf16(b0[ks], a[mi][ks], acc, 0, 0, 0);
            *(f32x4*)&tile[p][mi * 16 + lr][w * 16 + lg * 4] = acc;
        }
        __syncthreads();                   // single barrier per iteration
        {
            int gcol = nt * 64 + scol;
            bool ok = gcol < N_SERVICES;
            f32x4 bv = {};
            if (ok) bv = *(const f32x4*)&bias[gcol];
            float* ob = out + (size_t)m_base * N_SERVICES + gcol;
#pragma unroll
            for (int si = 0; si < 8; ++si) {
                int row = w * 32 + si * 4 + lg;
                f32x4 v = *(const f32x4*)&tile[p][row][scol] + bv;
                if (ok)
                    __builtin_nontemporal_store(
                        v, (f32x4*)(ob + (size_t)row * N_SERVICES));
            }
        }
        p ^= 1;
#pragma unroll
        for (int ks = 0; ks < 4; ++ks) b0[ks] = b1[ks];
    }
}

// ---------------- launch ----------------

extern "C" void kernel_launch(void* const* d_in, const int* in_sizes, int n_in,
                              void* d_out, int out_size, void* d_ws, size_t ws_size,
                              hipStream_t stream) {
    const int*   user_idx    = (const int*)d_in[0];
    const int*   ctx_idx     = (const int*)d_in[1];
    const int*   ei          = (const int*)d_in[2];
    const float* user_emb    = (const float*)d_in[3];
    const float* service_emb = (const float*)d_in[4];
    const float* W1          = (const float*)d_in[5];
    const float* b1          = (const float*)d_in[6];
    const float* W2          = (const float*)d_in[7];
    const float* b2          = (const float*)d_in[8];
    const float* fcW         = (const float*)d_in[9];
    const float* fcb         = (const float*)d_in[10];
    float* out = (float*)d_out;

    const int* src = ei;
    const int* dst = ei + N_EDGES;

    char* ws = (char*)d_ws;
    float*          dis       = (float*)(ws);                    // 200,000
    unsigned short* h1        = (unsigned short*)(ws + 200000);  // 3,200,000 (bf16 h1')
    unsigned short* h2b       = (unsigned short*)(ws + 3400000); // 3,200,000 (bf16 h2')
    unsigned short* partial   = (unsigned short*)(ws + 6600000); // 6,400,000
    unsigned short* xb        = (unsigned short*)(ws + 13000000);//   524,288
    short*          Wt        = (short*)(ws + 13524288);         // 12,812,288
    int*            row_start = (int*)(ws + 26336576);           // 200,004
    int*            csr_src   = (int*)(ws + 26736580);           // 6,400,000
    int*            tmp       = (int*)(ws + 26736580);           // 200,000 overlay (dead before k_fill)
    int*            blocksum  = (int*)(ws + 33136580);           // 1,024  (total ~33.1 MB)

    // cvtW ∥ tiled count (merged)
    k_prep<<<CVT_BLKS + R_RANGES * C_CHUNKS, 256, 0, stream>>>(fcW, Wt, dst, partial);
    k_scan_block<<<196, 256, 0, stream>>>(partial, dis, tmp, blocksum);
    // fused: scan finish + in-place chunk offsets ∥ layer-1 transform
    k_scanfin_tf<<<196 + 6250, 256, 0, stream>>>(tmp, blocksum, row_start,
                                                 partial, service_emb, W1, dis, h1);
    k_fill<<<R_RANGES * C_CHUNKS, 256, 0, stream>>>(src, dst, row_start, partial, csr_src);

    // fused layer-1 agg + ReLU + layer-2 transform (g1 never leaves LDS)
    k_agg_tf<<<3125, 256, 0, stream>>>(row_start, csr_src, dis,
                                       (const unsigned int*)h1, b1, W2, h2b);
    // layer-2 agg (slot-parallel) + user gather -> xb (bf16)
    k_agg_gather<<<512, 256, 0, stream>>>(row_start, csr_src, dis,
                                          (const unsigned int*)h2b, b2,
                                          user_idx, ctx_idx, user_emb, xb);

    k_gemm3<<<GEMM_BLKS, 256, 0, stream>>>((const short*)xb, Wt, fcb, out);
}